// Round 4
// baseline (393.969 us; speedup 1.0000x reference)
//
#include <hip/hip_runtime.h>

// Problem constants (B=8, S=1024, H=128, rel rows R=129)
constexpr int Bn = 8, Sn = 1024, Hn = 128, Rn = 129, RLD = 132;
constexpr float INV_SCALE = 0.088388347648318447f; // 1/sqrt(128)
constexpr size_t YEL = (size_t)Bn * Sn * Hn;       // y output elements

typedef short bf16x8 __attribute__((ext_vector_type(8)));
typedef short v4s __attribute__((ext_vector_type(4)));
typedef float f32x4 __attribute__((ext_vector_type(4)));
typedef int v4i __attribute__((ext_vector_type(4)));

__device__ __forceinline__ float bf2f(short s) {
    unsigned u = ((unsigned)(unsigned short)s) << 16;
    float f; __builtin_memcpy(&f, &u, 4); return f;
}
__device__ __forceinline__ short f2bf(float f) {
    unsigned u; __builtin_memcpy(&u, &f, 4);
    unsigned r = (u + 0x7fffu + ((u >> 16) & 1u)) >> 16;
    return (short)(r & 0xffffu);
}
__device__ __forceinline__ float ldin(const void* p, size_t i, int f32m) {
    return f32m ? ((const float*)p)[i] : bf2f(((const short*)p)[i]);
}

// dtype probe: f32 reinterpreted as shorts -> ~74% of low halves have bf16
// exponent outside [0x5F,0xA0]; true bf16 N(0,1) has ~none.
__global__ void detect_dtype(const void* x, int* flag) {
    const int t = threadIdx.x; // 64 threads
    const unsigned short* p = (const unsigned short*)x;
    int bad = 0;
    for (int i = t; i < 1024; i += 64) {
        int e = (p[i] >> 7) & 0xFF;
        bad += (e < 0x5F || e > 0xA0) ? 1 : 0;
    }
    for (int off = 32; off; off >>= 1) bad += __shfl_down(bad, off);
    if (t == 0) flag[0] = (bad > 100) ? 1 : 0;
}

// relcat[p][0:128]=rh, [128:256]=rh, [256:384]=rl  (K=384 companion of [qh|ql|qh])
__global__ __launch_bounds__(384) void build_relcat(
    const void* __restrict__ rel_k, short* __restrict__ relcat,
    const int* __restrict__ dflag)
{
    const int p = blockIdx.x;      // 0..128
    const int c = threadIdx.x;     // 0..383
    const int f32m = dflag[0];
    const int j = (c < 256) ? (c & 127) : (c - 256);
    short outv;
    if (f32m) {
        float v = ((const float*)rel_k)[p * Hn + j];
        short h = f2bf(v);
        outv = (c < 256) ? h : f2bf(v - bf2f(h));
    } else {
        short h = ((const short*)rel_k)[p * Hn + j];
        outv = (c < 256) ? h : (short)0;
    }
    relcat[p * 384 + c] = outv;
}

// fp32 VALU projection: out = X @ W + b.  QSPLIT: hi/lo bf16 pair (ld 256),
// else plain bf16 (ld 128). 64-row blocks, 256 threads, 8x4 outputs/thread.
template<bool QSPLIT>
__global__ __launch_bounds__(256) void proj(
    const void* __restrict__ X, const void* __restrict__ W,
    const void* __restrict__ bias, short* __restrict__ out,
    const int* __restrict__ dflag)
{
    __shared__ float xs[64][128];
    __shared__ float wsm[32][128];
    const int f32m = dflag[0];
    const int tid = threadIdx.x;
    const int row0 = blockIdx.x * 64;

    if (f32m) {
        const float* Xf = (const float*)X;
#pragma unroll
        for (int it = 0; it < 8; ++it) {
            int u = tid + it * 256;          // 0..2047 float4-units
            int r = u >> 5, c4 = (u & 31) * 4;
            *(float4*)&xs[r][c4] = *(const float4*)(Xf + (size_t)(row0 + r) * 128 + c4);
        }
    } else {
        const short* Xb = (const short*)X;
#pragma unroll
        for (int it = 0; it < 4; ++it) {
            int u = tid + it * 256;          // 0..1023 bf16x8-units
            int r = u >> 4, c8 = (u & 15) * 8;
            bf16x8 w = *(const bf16x8*)(Xb + (size_t)(row0 + r) * 128 + c8);
#pragma unroll
            for (int j = 0; j < 8; ++j) xs[r][c8 + j] = bf2f(w[j]);
        }
    }

    const int rg = tid >> 5;   // 8 row-groups of 8 rows
    const int cg = tid & 31;   // 32 col-groups; cols cg + c*32 (conflict-free)
    float acc[8][4] = {};

    for (int kc = 0; kc < 128; kc += 32) {
        if (f32m) {
            const float* Wf = (const float*)W;
#pragma unroll
            for (int it = 0; it < 4; ++it) {
                int u = tid + it * 256;      // 0..1023 float4-units
                int kk = u >> 5, c4 = (u & 31) * 4;
                *(float4*)&wsm[kk][c4] = *(const float4*)(Wf + (size_t)(kc + kk) * 128 + c4);
            }
        } else {
            const short* Wb = (const short*)W;
#pragma unroll
            for (int it = 0; it < 2; ++it) {
                int u = tid + it * 256;      // 0..511 bf16x8-units
                int kk = u >> 4, c8 = (u & 15) * 8;
                bf16x8 w = *(const bf16x8*)(Wb + (size_t)(kc + kk) * 128 + c8);
#pragma unroll
                for (int j = 0; j < 8; ++j) wsm[kk][c8 + j] = bf2f(w[j]);
            }
        }
        __syncthreads();
#pragma unroll 8
        for (int kk = 0; kk < 32; ++kk) {
            float wv[4];
#pragma unroll
            for (int c = 0; c < 4; ++c) wv[c] = wsm[kk][cg + c * 32];
#pragma unroll
            for (int r = 0; r < 8; ++r) {
                float xv = xs[rg * 8 + r][kc + kk];
#pragma unroll
                for (int c = 0; c < 4; ++c) acc[r][c] += xv * wv[c];
            }
        }
        __syncthreads();
    }

#pragma unroll
    for (int c = 0; c < 4; ++c) {
        int col = cg + c * 32;
        float bv = ldin(bias, col, f32m);
#pragma unroll
        for (int r = 0; r < 8; ++r) {
            int row = row0 + rg * 8 + r;
            float v = acc[r][c] + bv;
            if (QSPLIT) {
                short h = f2bf(v);
                out[(size_t)row * 256 + col] = h;
                out[(size_t)row * 256 + 128 + col] = f2bf(v - bf2f(h));
            } else {
                out[(size_t)row * 128 + col] = f2bf(v);
            }
        }
    }
}

// 64x64-tile bf16 MFMA GEMM, fp32 accumulate.
// EPI: 1 = f32 store (col < Ncols) ; 2 = scores epilogue (f32, + qrel gather)
// ADUP3: A columns [256,384) alias [0,128) (K=384 hi/lo/hi trick), lda=256
// AEXT:  A is an external/runtime-dtype buffer (attn) -> branch on dflag
template<bool TRANS_B, int EPI, bool ADUP3, bool AEXT>
__global__ __launch_bounds__(256) void gemm64(
    const void* __restrict__ Av, size_t Aeoff, size_t Abst, int lda,
    const short* __restrict__ Bm, size_t Bbst, int ldb, int Brows,
    void* __restrict__ Cv, size_t Cbst, int ldc, int Ncols,
    const float* __restrict__ qrel, int rowoff,
    int K, const int* __restrict__ dflag)
{
    __shared__ short As[64][72];
    __shared__ short Bs[64][72];   // Bs[n][k]

    const int f32m = dflag[0];
    const int tid = threadIdx.x;
    const int wave = tid >> 6, lane = tid & 63;
    const int quad = lane >> 4, l15 = lane & 15;
    const int z = blockIdx.z;
    const int row0 = blockIdx.x * 64, col0 = blockIdx.y * 64;
    const size_t abase = Aeoff + (size_t)z * Abst;
    const size_t bbase = (size_t)z * Bbst;

    f32x4 acc[4] = {};

    for (int kc = 0; kc < K; kc += 64) {
        // ---- stage A tile 64x64
        if (AEXT && f32m) {
            const float* Af = (const float*)Av;
#pragma unroll
            for (int it = 0; it < 4; ++it) {
                int u = tid + it * 256;
                int r = u >> 4, c4 = (u & 15) * 4;
                float4 w = *(const float4*)(Af + abase + (size_t)(row0 + r) * lda + kc + c4);
                v4s pk = { f2bf(w.x), f2bf(w.y), f2bf(w.z), f2bf(w.w) };
                *(v4s*)&As[r][c4] = pk;
            }
        } else {
            const short* Ab = (const short*)Av;
#pragma unroll
            for (int it = 0; it < 2; ++it) {
                int u = tid + it * 256;
                int r = u >> 3, c8 = (u & 7) * 8;
                int srcc = kc + c8;
                if (ADUP3 && srcc >= 256) srcc -= 256;
                *(v4i*)&As[r][c8] = *(const v4i*)(Ab + abase + (size_t)(row0 + r) * lda + srcc);
            }
        }
        // ---- stage B tile (always internal bf16)
        if (TRANS_B) {
#pragma unroll
            for (int it = 0; it < 2; ++it) {
                int u = tid + it * 256;
                int r = u >> 3, c8 = (u & 7) * 8;
                v4i val = {0, 0, 0, 0};
                if (col0 + r < Brows)
                    val = *(const v4i*)(Bm + bbase + (size_t)(col0 + r) * ldb + kc + c8);
                *(v4i*)&Bs[r][c8] = val;
            }
        } else {
#pragma unroll
            for (int it = 0; it < 16; ++it) {
                int e = tid + it * 256;        // 0..4095
                int kk = e >> 6, nn = e & 63;
                Bs[nn][kk] = Bm[bbase + (size_t)(kc + kk) * ldb + col0 + nn];
            }
        }
        __syncthreads();

#pragma unroll
        for (int ks = 0; ks < 64; ks += 32) {
            bf16x8 af = *(const bf16x8*)&As[wave * 16 + l15][ks + quad * 8];
#pragma unroll
            for (int nt = 0; nt < 4; ++nt) {
                bf16x8 bf = *(const bf16x8*)&Bs[nt * 16 + l15][ks + quad * 8];
                acc[nt] = __builtin_amdgcn_mfma_f32_16x16x32_bf16(af, bf, acc[nt], 0, 0, 0);
            }
        }
        __syncthreads();
    }

    // epilogue: D row=quad*4+r, col=l15 (m89/m91-verified)
    const int rloc0 = wave * 16 + quad * 4;
#pragma unroll
    for (int nt = 0; nt < 4; ++nt) {
        int col = col0 + nt * 16 + l15;
#pragma unroll
        for (int r = 0; r < 4; ++r) {
            int row = row0 + rloc0 + r;
            float v = acc[nt][r];
            if (EPI == 1) {
                if (col < Ncols)
                    ((float*)Cv)[(size_t)z * Cbst + (size_t)row * ldc + col] = v;
            } else { // EPI == 2: scores
                int d = col - (row + rowoff);
                d = (d < -64) ? -64 : (d > 64 ? 64 : d);
                float qr = qrel[(size_t)row * RLD + (d + 64)];
                ((float*)Cv)[(size_t)z * Cbst + (size_t)row * ldc + col] = v * INV_SCALE + qr;
            }
        }
    }
}

// Row softmax over fp32 score chunk -> attn (dtype per flag) + f32 arel.
// arel[i][p]: p=0: sum_{j<=i-64}; p=128: sum_{j>=i+64}; p=1..127: attn[i,i+p-64]
__global__ __launch_bounds__(256) void softmax_arel(
    const float* __restrict__ scores, void* __restrict__ dout, size_t attn_eoff,
    float* __restrict__ arelf, int i0, const int* __restrict__ dflag)
{
    const int iloc = blockIdx.x;
    const int i = i0 + iloc;           // row within batch
    const int t = threadIdx.x;
    const int wave = t >> 6, lane = t & 63;
    const int f32m = dflag[0];
    __shared__ float buf[Sn];
    __shared__ float redm[4], reds[4], redl[4], redh[4];

    const float* srow = scores + (size_t)iloc * Sn;
    float4 v = ((const float4*)srow)[t];

    float mx = fmaxf(fmaxf(v.x, v.y), fmaxf(v.z, v.w));
    for (int off = 32; off; off >>= 1) mx = fmaxf(mx, __shfl_down(mx, off));
    if (lane == 0) redm[wave] = mx;
    __syncthreads();
    mx = fmaxf(fmaxf(redm[0], redm[1]), fmaxf(redm[2], redm[3]));

    float e0 = __expf(v.x - mx), e1 = __expf(v.y - mx);
    float e2 = __expf(v.z - mx), e3 = __expf(v.w - mx);
    float s = e0 + e1 + e2 + e3;
    for (int off = 32; off; off >>= 1) s += __shfl_down(s, off);
    if (lane == 0) reds[wave] = s;
    __syncthreads();
    s = reds[0] + reds[1] + reds[2] + reds[3];
    float inv = 1.0f / s;
    e0 *= inv; e1 *= inv; e2 *= inv; e3 *= inv;

    const size_t ebase = attn_eoff + (size_t)iloc * Sn + 4 * t;
    if (f32m) {
        float4 fv; fv.x = e0; fv.y = e1; fv.z = e2; fv.w = e3;
        *(float4*)((float*)dout + ebase) = fv;
    } else {
        ushort4 pk;
        pk.x = (unsigned short)f2bf(e0); pk.y = (unsigned short)f2bf(e1);
        pk.z = (unsigned short)f2bf(e2); pk.w = (unsigned short)f2bf(e3);
        *(ushort4*)((short*)dout + ebase) = pk;
    }

    buf[4 * t + 0] = e0; buf[4 * t + 1] = e1;
    buf[4 * t + 2] = e2; buf[4 * t + 3] = e3;
    __syncthreads();

    float* arow = arelf + (size_t)iloc * RLD;
    if (t >= 1 && t < 128) {
        int j = i + t - 64;
        arow[t] = (j >= 0 && j < Sn) ? buf[j] : 0.f;
    }
    float lo = 0.f, hi = 0.f;
    const int jlo = i - 64, jhi = i + 64;
    for (int j = t; j < Sn; j += 256) {
        float a = buf[j];
        lo += (j <= jlo) ? a : 0.f;
        hi += (j >= jhi) ? a : 0.f;
    }
    for (int off = 32; off; off >>= 1) { lo += __shfl_down(lo, off); hi += __shfl_down(hi, off); }
    if (lane == 0) { redl[wave] = lo; redh[wave] = hi; }
    __syncthreads();
    if (t == 0) arow[0]   = redl[0] + redl[1] + redl[2] + redl[3];
    if (t == 1) arow[128] = redh[0] + redh[1] + redh[2] + redh[3];
}

// Per-row: ctx += arel@rel_v ; out = ctx@Wo + bo + x ; LayerNorm -> y
__global__ __launch_bounds__(128) void out_ln(
    const float* __restrict__ ctx, const float* __restrict__ arel_all,
    const void* __restrict__ rel_v, const void* __restrict__ Wo,
    const void* __restrict__ bo, const void* __restrict__ x,
    const void* __restrict__ gamma, const void* __restrict__ beta,
    void* __restrict__ y, const int* __restrict__ dflag)
{
    const int row = blockIdx.x;       // b*S + i
    const int t = threadIdx.x;        // 0..127
    const int wave = t >> 6, lane = t & 63;
    const int f32m = dflag[0];
    __shared__ float asv[132];
    __shared__ float ch[128];
    __shared__ float r1[2], r2[2];

    const float* arow = arel_all + (size_t)row * RLD;
    asv[t] = arow[t];
    if (t == 0) asv[128] = arow[128];
    float c = ctx[(size_t)row * Hn + t];
    __syncthreads();

    float extra = 0.f;
    if (f32m) {
        const float* rv = (const float*)rel_v;
        for (int p = 0; p < Rn; ++p) extra += asv[p] * rv[p * Hn + t];
    } else {
        const short* rv = (const short*)rel_v;
        for (int p = 0; p < Rn; ++p) extra += asv[p] * bf2f(rv[p * Hn + t]);
    }
    ch[t] = c + extra;
    __syncthreads();

    float acc = 0.f;
    if (f32m) {
        const float* wo = (const float*)Wo;
        for (int h = 0; h < Hn; ++h) acc += ch[h] * wo[h * Hn + t];
    } else {
        const short* wo = (const short*)Wo;
        for (int h = 0; h < Hn; ++h) acc += ch[h] * bf2f(wo[h * Hn + t]);
    }
    float yv = acc + ldin(bo, t, f32m) + ldin(x, (size_t)row * Hn + t, f32m);

    float s = yv;
    for (int off = 32; off; off >>= 1) s += __shfl_down(s, off);
    if (lane == 0) r1[wave] = s;
    __syncthreads();
    float mu = (r1[0] + r1[1]) * (1.f / 128.f);
    float d = yv - mu;
    float sq = d * d;
    for (int off = 32; off; off >>= 1) sq += __shfl_down(sq, off);
    if (lane == 0) r2[wave] = sq;
    __syncthreads();
    float var = (r2[0] + r2[1]) * (1.f / 128.f);

    float outv = d * rsqrtf(var + 1e-5f) * ldin(gamma, t, f32m) + ldin(beta, t, f32m);
    if (f32m) ((float*)y)[(size_t)row * Hn + t] = outv;
    else      ((short*)y)[(size_t)row * Hn + t] = f2bf(outv);
}

extern "C" void kernel_launch(void* const* d_in, const int* in_sizes, int n_in,
                              void* d_out, int out_size, void* d_ws, size_t ws_size,
                              hipStream_t stream) {
    const void* x     = d_in[0];
    const void* Wq    = d_in[1];
    const void* bq    = d_in[2];
    const void* Wk    = d_in[3];
    const void* bk    = d_in[4];
    const void* Wv    = d_in[5];
    const void* bv    = d_in[6];
    const void* rel_k = d_in[7];
    const void* rel_v = d_in[8];
    const void* Wo    = d_in[9];
    const void* bo    = d_in[10];
    const void* gamma = d_in[11];
    const void* beta  = d_in[12];

    // Workspace (~14.9 MB):
    char* ws = (char*)d_ws;
    short* qcat   = (short*)(ws + 0);          // 8192x256 bf16 hi|lo (4 MB)
    short* kh     = (short*)(ws + 4194304);    // 8192x128 bf16 (2 MB)
    short* vh     = (short*)(ws + 6291456);    // 8192x128 bf16 (2 MB)
    float* qrel   = (float*)(ws + 8388608);    // 8192x132 f32 (4,325,376 B); arel overlays 1:1
    float* scb    = (float*)(ws + 12713984);   // 512x1024 f32 chunk (2 MB)
    short* relcat = (short*)(ws + 14811136);   // 129x384 bf16 (99,072 B)
    int*   dflag  = (int*)(ws + 14910208);     // 4 B
    float* ctxf   = (float*)qcat;              // overlay (qcat dead after scores)

    // 0) dtype probe + relcat
    detect_dtype<<<1, 64, 0, stream>>>(x, dflag);
    build_relcat<<<Rn, 384, 0, stream>>>(rel_k, relcat, dflag);

    // 1) fp32 projections: q -> hi/lo qcat; k, v -> bf16
    proj<true ><<<128, 256, 0, stream>>>(x, Wq, bq, qcat, dflag);
    proj<false><<<128, 256, 0, stream>>>(x, Wk, bk, kh, dflag);
    proj<false><<<128, 256, 0, stream>>>(x, Wv, bv, vh, dflag);

    // 2) qrel = [qh|ql|qh] @ [rh|rh|rl]^T  (K=384, fp32-faithful)
    gemm64<true, 1, true, false><<<dim3(128, 3, 1), 256, 0, stream>>>(
        qcat, 0, 0, 256, relcat, 0, 384, Rn,
        qrel, 0, RLD, Rn, nullptr, 0, 384, dflag);

    // 3+4) per (batch, 512-row chunk): scores -> scb ; softmax -> attn + arel(f32, overlays qrel)
    for (int b = 0; b < Bn; ++b) {
        for (int c = 0; c < 2; ++c) {
            const size_t rowg = (size_t)b * Sn + c * 512;
            gemm64<true, 2, false, false><<<dim3(8, 16, 1), 256, 0, stream>>>(
                qcat + rowg * 256, 0, 0, 256,
                kh + (size_t)b * Sn * Hn, 0, Hn, Sn,
                scb, 0, Sn, Sn,
                qrel + rowg * RLD, c * 512, Hn, dflag);
            softmax_arel<<<dim3(512, 1, 1), 256, 0, stream>>>(
                scb, d_out, YEL + rowg * Sn,
                qrel + rowg * RLD, c * 512, dflag);
        }
    }

    // 5) ctx = attn @ v -> f32 (overlays qcat)
    gemm64<false, 1, false, true><<<dim3(Sn / 64, Hn / 64, Bn), 256, 0, stream>>>(
        d_out, YEL, (size_t)Sn * Sn, Sn, vh, (size_t)Sn * Hn, Hn, Sn,
        ctxf, (size_t)Sn * Hn, Hn, Hn, nullptr, 0, Sn, dflag);

    // 6) ctx += arel@rel_v ; out-proj + residual + LayerNorm -> y
    out_ln<<<dim3(Bn * Sn, 1, 1), 128, 0, stream>>>(
        ctxf, qrel, rel_v, Wo, bo, x, gamma, beta, d_out, dflag);
}

// Round 5
// 193.516 us; speedup vs baseline: 2.0358x; 2.0358x over previous
//
#include <hip/hip_runtime.h>

// B=8, S=1024, H=128, rel rows R=129. All inputs/outputs are float32.
constexpr int Bn = 8, Sn = 1024, Hn = 128, Rn = 129, RLD = 132;
constexpr float INV_SCALE = 0.088388347648318447f; // 1/sqrt(128)
constexpr size_t YEL = (size_t)Bn * Sn * Hn;       // y output elements

typedef short bf16x8 __attribute__((ext_vector_type(8)));
typedef short v4s __attribute__((ext_vector_type(4)));
typedef float f32x4 __attribute__((ext_vector_type(4)));
typedef int v4i __attribute__((ext_vector_type(4)));

__device__ __forceinline__ float bf2f(short s) {
    unsigned u = ((unsigned)(unsigned short)s) << 16;
    float f; __builtin_memcpy(&f, &u, 4); return f;
}
__device__ __forceinline__ short f2bf(float f) {
    unsigned u; __builtin_memcpy(&u, &f, 4);
    unsigned r = (u + 0x7fffu + ((u >> 16) & 1u)) >> 16;
    return (short)(r & 0xffffu);
}

// relcat[p] = [rh(128) | rh(128) | rl(128)]  — K=384 companion of [qh|ql|qh]
__global__ __launch_bounds__(384) void build_relcat(
    const float* __restrict__ rel_k, short* __restrict__ relcat)
{
    const int p = blockIdx.x, c = threadIdx.x;
    const int j = (c < 256) ? (c & 127) : (c - 256);
    float v = rel_k[p * Hn + j];
    short h = f2bf(v);
    relcat[p * 384 + c] = (c < 256) ? h : f2bf(v - bf2f(h));
}

// BcatT[n][k] (ld 320): k<128 -> Wo[k][n]; 128<=k<257 -> (rel_v@Wo)[k-128][n]; else 0
__global__ __launch_bounds__(256) void build_bcat(
    const float* __restrict__ rel_v, const float* __restrict__ Wo,
    short* __restrict__ BcatT)
{
    int idx = blockIdx.x * 256 + threadIdx.x;     // 0..40959 (320x128)
    int k = idx >> 7, n = idx & 127;
    float v;
    if (k < 128) v = Wo[k * Hn + n];
    else if (k < 257) {
        int p = k - 128; float a = 0.f;
        for (int h = 0; h < Hn; ++h) a += rel_v[p * Hn + h] * Wo[h * Hn + n];
        v = a;
    } else v = 0.f;
    BcatT[n * 320 + k] = f2bf(v);
}

// Fused fp32 VALU projections: y-dim selects Q (hi/lo qcat + qh), K (kh), V (vT).
__global__ __launch_bounds__(256) void proj(
    const float* __restrict__ X,
    const float* __restrict__ Wq, const float* __restrict__ bq,
    const float* __restrict__ Wk, const float* __restrict__ bk,
    const float* __restrict__ Wv, const float* __restrict__ bv,
    short* __restrict__ qh, short* __restrict__ qcat,
    short* __restrict__ kh, short* __restrict__ vT)
{
    __shared__ float xs[64][128];
    __shared__ float wsm[32][128];
    const int tid = threadIdx.x;
    const int sel = blockIdx.y;
    const int row0 = blockIdx.x * 64;
    const float* W = (sel == 0) ? Wq : (sel == 1) ? Wk : Wv;
    const float* bias = (sel == 0) ? bq : (sel == 1) ? bk : bv;

#pragma unroll
    for (int it = 0; it < 8; ++it) {
        int u = tid + it * 256;              // 0..2047 float4-units
        int r = u >> 5, c4 = (u & 31) * 4;
        *(float4*)&xs[r][c4] = *(const float4*)(X + (size_t)(row0 + r) * 128 + c4);
    }

    const int rg = tid >> 5, cg = tid & 31;
    float acc[8][4] = {};
    for (int kc = 0; kc < 128; kc += 32) {
#pragma unroll
        for (int it = 0; it < 4; ++it) {
            int u = tid + it * 256;
            int kk = u >> 5, c4 = (u & 31) * 4;
            *(float4*)&wsm[kk][c4] = *(const float4*)(W + (size_t)(kc + kk) * 128 + c4);
        }
        __syncthreads();
#pragma unroll 8
        for (int kk = 0; kk < 32; ++kk) {
            float wv[4];
#pragma unroll
            for (int c = 0; c < 4; ++c) wv[c] = wsm[kk][cg + c * 32];
#pragma unroll
            for (int r = 0; r < 8; ++r) {
                float xv = xs[rg * 8 + r][kc + kk];
#pragma unroll
                for (int c = 0; c < 4; ++c) acc[r][c] += xv * wv[c];
            }
        }
        __syncthreads();
    }

#pragma unroll
    for (int c = 0; c < 4; ++c) {
        int col = cg + c * 32;
        float bv2 = bias[col];
#pragma unroll
        for (int r = 0; r < 8; ++r) {
            int row = row0 + rg * 8 + r;
            float v = acc[r][c] + bv2;
            short h = f2bf(v);
            if (sel == 0) {
                qh[(size_t)row * 128 + col] = h;
                qcat[(size_t)row * 256 + col] = h;
                qcat[(size_t)row * 256 + 128 + col] = f2bf(v - bf2f(h));
            } else if (sel == 1) {
                kh[(size_t)row * 128 + col] = h;
            } else {
                int b = row >> 10, i = row & (Sn - 1);
                vT[(size_t)b * 131072 + (size_t)col * 1024 + i] = h;
            }
        }
    }
}

// 64x64-tile bf16 MFMA GEMM. MODE 0: qrel=[qh|ql|qh]@relcat^T (K=384, f32 out, col<129)
// MODE 1: scores=qh@kh^T*scale + qrel-gather -> f32 attn region (K=128, z=batch)
// MODE 2: ctx partial = bf16(attn_f32)@vT^T, K-split 4, atomicAdd f32 (z=b*4+ks)
template<int MODE>
__global__ __launch_bounds__(256) void gemmk(
    const void* __restrict__ Av, const short* __restrict__ Bm,
    void* __restrict__ Cv, const float* __restrict__ qrel)
{
    __shared__ short As[64][72];
    __shared__ short Bs[64][72];

    const int tid = threadIdx.x;
    const int wave = tid >> 6, lane = tid & 63;
    const int quad = lane >> 4, l15 = lane & 15;
    const int row0 = blockIdx.x * 64, col0 = blockIdx.y * 64;
    const int z = blockIdx.z;
    const int b = (MODE == 2) ? (z >> 2) : z;
    const int kabs0 = (MODE == 2) ? ((z & 3) * 256) : 0;
    const int K = (MODE == 0) ? 384 : (MODE == 1) ? 128 : 256;

    f32x4 acc[4] = {};

    for (int kc = 0; kc < K; kc += 64) {
        // ---- stage A
        if (MODE == 2) {
            const float* Af = (const float*)Av + (size_t)b * Sn * Sn;
#pragma unroll
            for (int it = 0; it < 4; ++it) {
                int u = tid + it * 256;
                int r = u >> 4, c4 = (u & 15) * 4;
                float4 w = *(const float4*)(Af + (size_t)(row0 + r) * 1024 + kabs0 + kc + c4);
                v4s pk = { f2bf(w.x), f2bf(w.y), f2bf(w.z), f2bf(w.w) };
                *(v4s*)&As[r][c4] = pk;
            }
        } else {
            const short* Ab = (const short*)Av + (MODE == 1 ? (size_t)b * Sn * 128 : 0);
            const int lda = (MODE == 0) ? 256 : 128;
#pragma unroll
            for (int it = 0; it < 2; ++it) {
                int u = tid + it * 256;
                int r = u >> 3, c8 = (u & 7) * 8;
                int srcc = kc + c8;
                if (MODE == 0 && srcc >= 256) srcc -= 256;
                *(v4i*)&As[r][c8] = *(const v4i*)(Ab + (size_t)(row0 + r) * lda + srcc);
            }
        }
        // ---- stage B (TRANS layout: Bs[n][k])
        {
            const short* Bb = Bm +
                (MODE == 1 ? (size_t)b * Sn * 128 : MODE == 2 ? (size_t)b * 131072 : 0);
            const int ldb = (MODE == 0) ? 384 : (MODE == 1) ? 128 : 1024;
#pragma unroll
            for (int it = 0; it < 2; ++it) {
                int u = tid + it * 256;
                int r = u >> 3, c8 = (u & 7) * 8;
                v4i val = {0, 0, 0, 0};
                bool ok = (MODE == 0) ? (col0 + r < Rn) : true;
                if (ok)
                    val = *(const v4i*)(Bb + (size_t)(col0 + r) * ldb + kabs0 + kc + c8);
                *(v4i*)&Bs[r][c8] = val;
            }
        }
        __syncthreads();
#pragma unroll
        for (int ks = 0; ks < 64; ks += 32) {
            bf16x8 af = *(const bf16x8*)&As[wave * 16 + l15][ks + quad * 8];
#pragma unroll
            for (int nt = 0; nt < 4; ++nt) {
                bf16x8 bf = *(const bf16x8*)&Bs[nt * 16 + l15][ks + quad * 8];
                acc[nt] = __builtin_amdgcn_mfma_f32_16x16x32_bf16(af, bf, acc[nt], 0, 0, 0);
            }
        }
        __syncthreads();
    }

    const int rloc0 = wave * 16 + quad * 4;
#pragma unroll
    for (int nt = 0; nt < 4; ++nt) {
        int col = col0 + nt * 16 + l15;
#pragma unroll
        for (int r = 0; r < 4; ++r) {
            int row = row0 + rloc0 + r;
            float v = acc[nt][r];
            if (MODE == 0) {
                if (col < Rn) ((float*)Cv)[(size_t)row * RLD + col] = v;
            } else if (MODE == 1) {
                int d = col - row;
                d = (d < -64) ? -64 : (d > 64 ? 64 : d);
                float qr = qrel[(size_t)b * Sn * RLD + (size_t)row * RLD + (d + 64)];
                ((float*)Cv)[(size_t)b * Sn * Sn + (size_t)row * 1024 + col] = v * INV_SCALE + qr;
            } else {
                atomicAdd((float*)Cv + (size_t)b * Sn * 128 + (size_t)row * 128 + col, v);
            }
        }
    }
}

// In-place row softmax on f32 attn region + f32 arel (overlays qrel) + zero ctx row.
__global__ __launch_bounds__(256) void softmax_arel(
    float* __restrict__ attn, float* __restrict__ arel, float* __restrict__ ctx)
{
    const int row = blockIdx.x;        // 0..8191
    const int i = row & (Sn - 1);
    const int t = threadIdx.x;
    const int wave = t >> 6, lane = t & 63;
    __shared__ float buf[Sn];
    __shared__ float redm[4], reds[4], redl[4], redh[4];

    float* srow = attn + (size_t)row * Sn;
    float4 v = ((const float4*)srow)[t];

    float mx = fmaxf(fmaxf(v.x, v.y), fmaxf(v.z, v.w));
    for (int off = 32; off; off >>= 1) mx = fmaxf(mx, __shfl_down(mx, off));
    if (lane == 0) redm[wave] = mx;
    __syncthreads();
    mx = fmaxf(fmaxf(redm[0], redm[1]), fmaxf(redm[2], redm[3]));

    float e0 = __expf(v.x - mx), e1 = __expf(v.y - mx);
    float e2 = __expf(v.z - mx), e3 = __expf(v.w - mx);
    float s = e0 + e1 + e2 + e3;
    for (int off = 32; off; off >>= 1) s += __shfl_down(s, off);
    if (lane == 0) reds[wave] = s;
    __syncthreads();
    s = reds[0] + reds[1] + reds[2] + reds[3];
    float inv = 1.0f / s;
    e0 *= inv; e1 *= inv; e2 *= inv; e3 *= inv;

    float4 fv; fv.x = e0; fv.y = e1; fv.z = e2; fv.w = e3;
    ((float4*)srow)[t] = fv;

    buf[4 * t + 0] = e0; buf[4 * t + 1] = e1;
    buf[4 * t + 2] = e2; buf[4 * t + 3] = e3;

    // zero this row's ctx accumulator (threads 0..31, float4)
    if (t < 32) {
        float4 zz = {0.f, 0.f, 0.f, 0.f};
        *(float4*)(ctx + (size_t)row * 128 + 4 * t) = zz;
    }
    __syncthreads();

    float* arow = arel + (size_t)row * RLD;
    if (t >= 1 && t < 128) {
        int j = i + t - 64;
        arow[t] = (j >= 0 && j < Sn) ? buf[j] : 0.f;
    }
    if (t >= 129 && t < 132) arow[t] = 0.f;
    float lo = 0.f, hi = 0.f;
    const int jlo = i - 64, jhi = i + 64;
    for (int j = t; j < Sn; j += 256) {
        float a = buf[j];
        lo += (j <= jlo) ? a : 0.f;
        hi += (j >= jhi) ? a : 0.f;
    }
    for (int off = 32; off; off >>= 1) { lo += __shfl_down(lo, off); hi += __shfl_down(hi, off); }
    if (lane == 0) { redl[wave] = lo; redh[wave] = hi; }
    __syncthreads();
    if (t == 0) arow[0]   = redl[0] + redl[1] + redl[2] + redl[3];
    if (t == 1) arow[128] = redh[0] + redh[1] + redh[2] + redh[3];
}

// y = LN( [bf16(ctx) | bf16(arel)] @ BcatT^T + bo + x ) * gamma + beta  (f32 out)
// 64 rows/block, K=320 (cols 0..127 ctx, 128..259 arel(132), 260.. zero).
__global__ __launch_bounds__(256) void ln_gemm(
    const float* __restrict__ ctx, const float* __restrict__ arel,
    const short* __restrict__ BcatT, const float* __restrict__ bo,
    const float* __restrict__ X, const float* __restrict__ gamma,
    const float* __restrict__ beta, float* __restrict__ y)
{
    __shared__ short As[64][72];
    __shared__ short Bs[128][72];
    const int tid = threadIdx.x;
    const int wave = tid >> 6, lane = tid & 63;
    const int quad = lane >> 4, l15 = lane & 15;
    const int r0 = blockIdx.x * 64;

    f32x4 acc[8] = {};

    for (int kc = 0; kc < 320; kc += 64) {
        // stage A
#pragma unroll
        for (int it = 0; it < 2; ++it) {
            int u = tid + it * 256;
            int r = u >> 3, c8 = (u & 7) * 8;
            int c = kc + c8;
            v4s lo4, hi4;
            if (c < 128) {
                const float* src = ctx + (size_t)(r0 + r) * 128 + c;
                float4 w0 = *(const float4*)src, w1 = *(const float4*)(src + 4);
                lo4 = v4s{ f2bf(w0.x), f2bf(w0.y), f2bf(w0.z), f2bf(w0.w) };
                hi4 = v4s{ f2bf(w1.x), f2bf(w1.y), f2bf(w1.z), f2bf(w1.w) };
            } else if (c < 256) {
                const float* src = arel + (size_t)(r0 + r) * RLD + (c - 128);
                float4 w0 = *(const float4*)src, w1 = *(const float4*)(src + 4);
                lo4 = v4s{ f2bf(w0.x), f2bf(w0.y), f2bf(w0.z), f2bf(w0.w) };
                hi4 = v4s{ f2bf(w1.x), f2bf(w1.y), f2bf(w1.z), f2bf(w1.w) };
            } else { // c in [256,320): arel idx c-128 in [128,192): valid < 132
                short tmp[8];
#pragma unroll
                for (int j = 0; j < 8; ++j) {
                    int ai = c - 128 + j;
                    tmp[j] = (ai < RLD) ? f2bf(arel[(size_t)(r0 + r) * RLD + ai]) : (short)0;
                }
                lo4 = v4s{ tmp[0], tmp[1], tmp[2], tmp[3] };
                hi4 = v4s{ tmp[4], tmp[5], tmp[6], tmp[7] };
            }
            *(v4s*)&As[r][c8] = lo4;
            *(v4s*)&As[r][c8 + 4] = hi4;
        }
        // stage B: Bs[n][k] <- BcatT[n*320 + kc+k]
#pragma unroll
        for (int it = 0; it < 4; ++it) {
            int u = tid + it * 256;          // 0..1023
            int n = u >> 3, c8 = (u & 7) * 8;
            *(v4i*)&Bs[n][c8] = *(const v4i*)(BcatT + (size_t)n * 320 + kc + c8);
        }
        __syncthreads();
#pragma unroll
        for (int ks = 0; ks < 64; ks += 32) {
            bf16x8 af = *(const bf16x8*)&As[wave * 16 + l15][ks + quad * 8];
#pragma unroll
            for (int nt = 0; nt < 8; ++nt) {
                bf16x8 bf = *(const bf16x8*)&Bs[nt * 16 + l15][ks + quad * 8];
                acc[nt] = __builtin_amdgcn_mfma_f32_16x16x32_bf16(af, bf, acc[nt], 0, 0, 0);
            }
        }
        __syncthreads();
    }

    // epilogue: +bo +x, row LayerNorm via 16-lane shfl_xor, f32 store
#pragma unroll
    for (int r = 0; r < 4; ++r) {
        int row = r0 + wave * 16 + quad * 4 + r;
        float vv[8], sum = 0.f;
#pragma unroll
        for (int nt = 0; nt < 8; ++nt) {
            int col = nt * 16 + l15;
            vv[nt] = acc[nt][r] + bo[col] + X[(size_t)row * 128 + col];
            sum += vv[nt];
        }
#pragma unroll
        for (int m = 1; m < 16; m <<= 1) sum += __shfl_xor(sum, m);
        float mu = sum * (1.f / 128.f);
        float vs = 0.f;
#pragma unroll
        for (int nt = 0; nt < 8; ++nt) { float d = vv[nt] - mu; vs += d * d; }
#pragma unroll
        for (int m = 1; m < 16; m <<= 1) vs += __shfl_xor(vs, m);
        float inv = rsqrtf(vs * (1.f / 128.f) + 1e-5f);
#pragma unroll
        for (int nt = 0; nt < 8; ++nt) {
            int col = nt * 16 + l15;
            y[(size_t)row * 128 + col] = (vv[nt] - mu) * inv * gamma[col] + beta[col];
        }
    }
}

extern "C" void kernel_launch(void* const* d_in, const int* in_sizes, int n_in,
                              void* d_out, int out_size, void* d_ws, size_t ws_size,
                              hipStream_t stream) {
    const float* x     = (const float*)d_in[0];
    const float* Wq    = (const float*)d_in[1];
    const float* bq    = (const float*)d_in[2];
    const float* Wk    = (const float*)d_in[3];
    const float* bk    = (const float*)d_in[4];
    const float* Wv    = (const float*)d_in[5];
    const float* bv    = (const float*)d_in[6];
    const float* rel_k = (const float*)d_in[7];
    const float* rel_v = (const float*)d_in[8];
    const float* Wo    = (const float*)d_in[9];
    const float* bo    = (const float*)d_in[10];
    const float* gamma = (const float*)d_in[11];
    const float* beta  = (const float*)d_in[12];

    // Workspace: 14,910,208 B total (== round-4-proven footprint).
    char* ws = (char*)d_ws;
    short* qh     = (short*)(ws + 0);          // 8192x128 bf16 [0,2M)
    short* kh     = (short*)(ws + 2097152);    // [2M,4M)
    short* vT     = (short*)(ws + 4194304);    // 8x128x1024 bf16 [4M,6M)
    short* qcat   = (short*)(ws + 6291456);    // 8192x256 bf16 hi|lo [6M,10M)
    float* qrel   = (float*)(ws + 10485760);   // 8192x132 f32 (4,325,376 B); arel overlays
    short* relcat = (short*)(ws + 14811136);   // 129x384 bf16 (99,072 B)
    short* BcatT  = (short*)relcat;            // 128x320 bf16 (81,920 B) — after qrel GEMM
    float* ctx    = (float*)(ws + 0);          // 8192x128 f32 overlays qh+kh (dead post-scores)

    float* y_out = (float*)d_out;
    float* attn  = (float*)d_out + YEL;        // 8x1024x1024 f32; scores staged here

    build_relcat<<<dim3(Rn), 384, 0, stream>>>(rel_k, relcat);
    proj<<<dim3(128, 3), 256, 0, stream>>>(x, Wq, bq, Wk, bk, Wv, bv, qh, qcat, kh, vT);

    // qrel = [qh|ql|qh] @ [rh|rh|rl]^T (fp32-faithful q)
    gemmk<0><<<dim3(128, 3, 1), 256, 0, stream>>>(qcat, relcat, qrel, nullptr);

    // BcatT build (overlays relcat — relcat dead after qrel GEMM; stream-ordered)
    build_bcat<<<dim3(160), 256, 0, stream>>>(rel_v, Wo, BcatT);

    // scores -> f32 attn region (single launch, 2048 blocks)
    gemmk<1><<<dim3(16, 16, Bn), 256, 0, stream>>>(qh, kh, attn, qrel);

    // in-place softmax + arel(f32, overlays qrel) + zero ctx
    softmax_arel<<<dim3(Bn * Sn), 256, 0, stream>>>(attn, qrel, ctx);

    // ctx = attn @ v, K-split 4, atomic f32 accumulate (1024 blocks)
    gemmk<2><<<dim3(16, 2, Bn * 4), 256, 0, stream>>>(attn, vT, ctx, nullptr);

    // y = LN([ctx|arel] @ [Wo; rel_v@Wo] + bo + x)
    ln_gemm<<<dim3(128), 256, 0, stream>>>(ctx, qrel, BcatT, bo, x, gamma, beta, y_out);
}

// Round 6
// 180.615 us; speedup vs baseline: 2.1813x; 1.0714x over previous
//
#include <hip/hip_runtime.h>

// B=8, S=1024, H=128, rel rows R=129. All inputs/outputs are float32.
constexpr int Bn = 8, Sn = 1024, Hn = 128, Rn = 129, RLD = 132;
constexpr float INV_SCALE = 0.088388347648318447f; // 1/sqrt(128)
constexpr size_t YEL = (size_t)Bn * Sn * Hn;       // y output elements

typedef short bf16x8 __attribute__((ext_vector_type(8)));
typedef short v4s __attribute__((ext_vector_type(4)));
typedef float f32x4 __attribute__((ext_vector_type(4)));
typedef int v4i __attribute__((ext_vector_type(4)));

__device__ __forceinline__ float bf2f(short s) {
    unsigned u = ((unsigned)(unsigned short)s) << 16;
    float f; __builtin_memcpy(&f, &u, 4); return f;
}
__device__ __forceinline__ short f2bf(float f) {
    unsigned u; __builtin_memcpy(&u, &f, 4);
    unsigned r = (u + 0x7fffu + ((u >> 16) & 1u)) >> 16;
    return (short)(r & 0xffffu);
}

// relcat[p] = [rh(128) | rh(128) | rl(128)]  — K=384 companion of [qh|ql|qh]
__global__ __launch_bounds__(384) void build_relcat(
    const float* __restrict__ rel_k, short* __restrict__ relcat)
{
    const int p = blockIdx.x, c = threadIdx.x;
    const int j = (c < 256) ? (c & 127) : (c - 256);
    float v = rel_k[p * Hn + j];
    short h = f2bf(v);
    relcat[p * 384 + c] = (c < 256) ? h : f2bf(v - bf2f(h));
}

// BcatT[n][k] (ld 320): k<128 -> Wo[k][n]; 128<=k<257 -> (rel_v@Wo)[k-128][n]; else 0
__global__ __launch_bounds__(256) void build_bcat(
    const float* __restrict__ rel_v, const float* __restrict__ Wo,
    short* __restrict__ BcatT)
{
    int idx = blockIdx.x * 256 + threadIdx.x;     // 0..40959 (320x128)
    int k = idx >> 7, n = idx & 127;
    float v;
    if (k < 128) v = Wo[k * Hn + n];
    else if (k < 257) {
        int p = k - 128; float a = 0.f;
        for (int h = 0; h < Hn; ++h) a += rel_v[p * Hn + h] * Wo[h * Hn + n];
        v = a;
    } else v = 0.f;
    BcatT[n * 320 + k] = f2bf(v);
}

// Fused fp32 VALU projections: y-dim selects Q (hi/lo qcat + qh), K (kh), V (vT).
__global__ __launch_bounds__(256) void proj(
    const float* __restrict__ X,
    const float* __restrict__ Wq, const float* __restrict__ bq,
    const float* __restrict__ Wk, const float* __restrict__ bk,
    const float* __restrict__ Wv, const float* __restrict__ bv,
    short* __restrict__ qh, short* __restrict__ qcat,
    short* __restrict__ kh, short* __restrict__ vT)
{
    __shared__ float xs[64][128];
    __shared__ float wsm[32][128];
    const int tid = threadIdx.x;
    const int sel = blockIdx.y;
    const int row0 = blockIdx.x * 64;
    const float* W = (sel == 0) ? Wq : (sel == 1) ? Wk : Wv;
    const float* bias = (sel == 0) ? bq : (sel == 1) ? bk : bv;

#pragma unroll
    for (int it = 0; it < 8; ++it) {
        int u = tid + it * 256;
        int r = u >> 5, c4 = (u & 31) * 4;
        *(float4*)&xs[r][c4] = *(const float4*)(X + (size_t)(row0 + r) * 128 + c4);
    }

    const int rg = tid >> 5, cg = tid & 31;
    float acc[8][4] = {};
    for (int kc = 0; kc < 128; kc += 32) {
#pragma unroll
        for (int it = 0; it < 4; ++it) {
            int u = tid + it * 256;
            int kk = u >> 5, c4 = (u & 31) * 4;
            *(float4*)&wsm[kk][c4] = *(const float4*)(W + (size_t)(kc + kk) * 128 + c4);
        }
        __syncthreads();
#pragma unroll 8
        for (int kk = 0; kk < 32; ++kk) {
            float wv[4];
#pragma unroll
            for (int c = 0; c < 4; ++c) wv[c] = wsm[kk][cg + c * 32];
#pragma unroll
            for (int r = 0; r < 8; ++r) {
                float xv = xs[rg * 8 + r][kc + kk];
#pragma unroll
                for (int c = 0; c < 4; ++c) acc[r][c] += xv * wv[c];
            }
        }
        __syncthreads();
    }

#pragma unroll
    for (int c = 0; c < 4; ++c) {
        int col = cg + c * 32;
        float bv2 = bias[col];
#pragma unroll
        for (int r = 0; r < 8; ++r) {
            int row = row0 + rg * 8 + r;
            float v = acc[r][c] + bv2;
            short h = f2bf(v);
            if (sel == 0) {
                qh[(size_t)row * 128 + col] = h;
                qcat[(size_t)row * 256 + col] = h;
                qcat[(size_t)row * 256 + 128 + col] = f2bf(v - bf2f(h));
            } else if (sel == 1) {
                kh[(size_t)row * 128 + col] = h;
            } else {
                int b = row >> 10, i = row & (Sn - 1);
                vT[(size_t)b * 131072 + (size_t)col * 1024 + i] = h;
            }
        }
    }
}

// qrel = [qh|ql|qh] @ [rh|rh|rl]^T  (K=384, f32-faithful q), 64x64 tiles
__global__ __launch_bounds__(256) void qrel_gemm(
    const short* __restrict__ qcat, const short* __restrict__ relcat,
    float* __restrict__ qrel)
{
    __shared__ short As[64][72];
    __shared__ short Bs[64][72];
    const int tid = threadIdx.x;
    const int wave = tid >> 6, lane = tid & 63;
    const int quad = lane >> 4, l15 = lane & 15;
    const int row0 = blockIdx.x * 64, col0 = blockIdx.y * 64;

    f32x4 acc[4] = {};
    for (int kc = 0; kc < 384; kc += 64) {
#pragma unroll
        for (int it = 0; it < 2; ++it) {
            int u = tid + it * 256;
            int r = u >> 3, c8 = (u & 7) * 8;
            int srcc = kc + c8;
            if (srcc >= 256) srcc -= 256;
            *(v4i*)&As[r][c8] = *(const v4i*)(qcat + (size_t)(row0 + r) * 256 + srcc);
        }
#pragma unroll
        for (int it = 0; it < 2; ++it) {
            int u = tid + it * 256;
            int r = u >> 3, c8 = (u & 7) * 8;
            v4i val = {0, 0, 0, 0};
            if (col0 + r < Rn)
                val = *(const v4i*)(relcat + (size_t)(col0 + r) * 384 + kc + c8);
            *(v4i*)&Bs[r][c8] = val;
        }
        __syncthreads();
#pragma unroll
        for (int ks = 0; ks < 64; ks += 32) {
            bf16x8 af = *(const bf16x8*)&As[wave * 16 + l15][ks + quad * 8];
#pragma unroll
            for (int nt = 0; nt < 4; ++nt) {
                bf16x8 bf = *(const bf16x8*)&Bs[nt * 16 + l15][ks + quad * 8];
                acc[nt] = __builtin_amdgcn_mfma_f32_16x16x32_bf16(af, bf, acc[nt], 0, 0, 0);
            }
        }
        __syncthreads();
    }
    const int rloc0 = wave * 16 + quad * 4;
#pragma unroll
    for (int nt = 0; nt < 4; ++nt) {
        int col = col0 + nt * 16 + l15;
#pragma unroll
        for (int r = 0; r < 4; ++r) {
            if (col < Rn)
                qrel[(size_t)(row0 + rloc0 + r) * RLD + col] = acc[nt][r];
        }
    }
}

// Fused scores+softmax+arel+ctx per 16-row strip. 512 threads (8 waves).
// LDS: Ssc[16][1028] f32 (65,792 B) + QrL[16][132] f32 (8,448 B) = 74,240 B.
// Pb[16][1032] bf16 (33,024 B) overlays Ssc after the phase-2a barrier.
__global__ __launch_bounds__(512) void fused_attn(
    const short* __restrict__ qh, const short* __restrict__ kh,
    const short* __restrict__ vT, const float* __restrict__ qrel_g,
    float* __restrict__ attn_g, float* __restrict__ arel_g,
    float* __restrict__ ctx_g)
{
    __shared__ __align__(16) float smem[18560];
    float* Ssc = smem;                 // [16][1028]
    float* QrL = smem + 16448;         // [16][132]
    short* Pb  = (short*)smem;         // [16][1032] overlay

    const int tid = threadIdx.x;
    const int w = tid >> 6, lane = tid & 63;
    const int quad = lane >> 4, l15 = lane & 15;
    const int bz = blockIdx.z;
    const int row0 = blockIdx.x * 16;                 // within batch
    const size_t grow0 = (size_t)bz * Sn + row0;      // global row base

    // stage qrel strip -> LDS (wave w: rows 2w, 2w+1)
#pragma unroll
    for (int rr = 0; rr < 2; ++rr) {
        int r = w * 2 + rr;
        const float* src = qrel_g + (grow0 + r) * RLD;
        QrL[r * 132 + lane] = src[lane];
        QrL[r * 132 + lane + 64] = src[lane + 64];
        if (lane < 4) QrL[r * 132 + 128 + lane] = src[128 + lane];
    }

    // phase 1: scores strip. A-frags: qh rows row0+l15 (direct global).
    bf16x8 afr[4];
#pragma unroll
    for (int kk = 0; kk < 4; ++kk)
        afr[kk] = *(const bf16x8*)(qh + (grow0 + l15) * 128 + kk * 32 + quad * 8);
    __syncthreads();   // QrL ready

#pragma unroll
    for (int nt = 0; nt < 8; ++nt) {
        int colb = w * 128 + nt * 16;
        f32x4 acc = {};
#pragma unroll
        for (int kk = 0; kk < 4; ++kk) {
            bf16x8 bfr = *(const bf16x8*)(kh + ((size_t)bz * Sn + colb + l15) * 128 + kk * 32 + quad * 8);
            acc = __builtin_amdgcn_mfma_f32_16x16x32_bf16(afr[kk], bfr, acc, 0, 0, 0);
        }
        int col = colb + l15;
#pragma unroll
        for (int r = 0; r < 4; ++r) {
            int lr = quad * 4 + r;
            int i = row0 + lr;
            int d = col - i; d = (d < -64) ? -64 : (d > 64 ? 64 : d);
            Ssc[lr * 1028 + col] = acc[r] * INV_SCALE + QrL[lr * 132 + d + 64];
        }
    }
    __syncthreads();   // scores complete

    // phase 2a: softmax, wave w owns rows 2w, 2w+1; lane owns cols [lane*16, +16)
    float av[2][16];
    float lov[2], hiv[2];
#pragma unroll
    for (int rr = 0; rr < 2; ++rr) {
        int lr = w * 2 + rr, i = row0 + lr;
        float* base = &Ssc[lr * 1028 + lane * 16];
        float4 x0 = *(float4*)(base + 0), x1 = *(float4*)(base + 4);
        float4 x2 = *(float4*)(base + 8), x3 = *(float4*)(base + 12);
        float* a = av[rr];
        a[0]=x0.x; a[1]=x0.y; a[2]=x0.z; a[3]=x0.w;
        a[4]=x1.x; a[5]=x1.y; a[6]=x1.z; a[7]=x1.w;
        a[8]=x2.x; a[9]=x2.y; a[10]=x2.z; a[11]=x2.w;
        a[12]=x3.x; a[13]=x3.y; a[14]=x3.z; a[15]=x3.w;
        float mx = a[0];
#pragma unroll
        for (int j = 1; j < 16; ++j) mx = fmaxf(mx, a[j]);
#pragma unroll
        for (int m = 1; m < 64; m <<= 1) mx = fmaxf(mx, __shfl_xor(mx, m));
        float s = 0.f;
#pragma unroll
        for (int j = 0; j < 16; ++j) { a[j] = __expf(a[j] - mx); s += a[j]; }
#pragma unroll
        for (int m = 1; m < 64; m <<= 1) s += __shfl_xor(s, m);
        float inv = 1.0f / s;
        float lo = 0.f, hi = 0.f;
#pragma unroll
        for (int j = 0; j < 16; ++j) {
            a[j] *= inv;
            int col = lane * 16 + j;
            lo += (col <= i - 64) ? a[j] : 0.f;
            hi += (col >= i + 64) ? a[j] : 0.f;
        }
#pragma unroll
        for (int m = 1; m < 64; m <<= 1) { lo += __shfl_xor(lo, m); hi += __shfl_xor(hi, m); }
        lov[rr] = lo; hiv[rr] = hi;
        // write attn f32 (the required output) — coalesced
        float* dst = attn_g + (grow0 + lr) * Sn + lane * 16;
        *(float4*)(dst + 0)  = float4{a[0], a[1], a[2], a[3]};
        *(float4*)(dst + 4)  = float4{a[4], a[5], a[6], a[7]};
        *(float4*)(dst + 8)  = float4{a[8], a[9], a[10], a[11]};
        *(float4*)(dst + 12) = float4{a[12], a[13], a[14], a[15]};
    }
    __syncthreads();   // all f32 score reads done -> safe to overlay Pb

    // phase 2b: write bf16 P into LDS
#pragma unroll
    for (int rr = 0; rr < 2; ++rr) {
        int lr = w * 2 + rr;
        short t16[16];
#pragma unroll
        for (int j = 0; j < 16; ++j) t16[j] = f2bf(av[rr][j]);
        v4i pk0, pk1;
        __builtin_memcpy(&pk0, t16, 16);
        __builtin_memcpy(&pk1, t16 + 8, 16);
        *(v4i*)&Pb[lr * 1032 + lane * 16] = pk0;
        *(v4i*)&Pb[lr * 1032 + lane * 16 + 8] = pk1;
    }
    __syncthreads();   // P visible to all

    // arel writes (overlay onto qrel rows — already consumed by this block)
#pragma unroll
    for (int rr = 0; rr < 2; ++rr) {
        int lr = w * 2 + rr, i = row0 + lr;
        float* arow = arel_g + (grow0 + lr) * RLD;
        {   // p = lane
            float v;
            if (lane == 0) v = lov[rr];
            else { int c = i + lane - 64; v = (c >= 0 && c < Sn) ? bf2f(Pb[lr * 1032 + c]) : 0.f; }
            arow[lane] = v;
        }
        {   // p = lane + 64 (64..127)
            int p = lane + 64;
            int c = i + p - 64;
            arow[p] = (c >= 0 && c < Sn) ? bf2f(Pb[lr * 1032 + c]) : 0.f;
        }
        if (lane < 4) {  // p = 128..131
            int p = lane + 128;
            arow[p] = (p == 128) ? hiv[rr] : 0.f;
        }
    }

    // phase 3: ctx = P @ v  (A from LDS Pb, B direct from vT)
    f32x4 cacc = {};
#pragma unroll 8
    for (int kk = 0; kk < 32; ++kk) {
        bf16x8 a = *(const bf16x8*)&Pb[l15 * 1032 + kk * 32 + quad * 8];
        bf16x8 b = *(const bf16x8*)(vT + (size_t)bz * 131072 + (size_t)(w * 16 + l15) * 1024 + kk * 32 + quad * 8);
        cacc = __builtin_amdgcn_mfma_f32_16x16x32_bf16(a, b, cacc, 0, 0, 0);
    }
#pragma unroll
    for (int r = 0; r < 4; ++r) {
        int lr = quad * 4 + r;
        ctx_g[(grow0 + lr) * 128 + w * 16 + l15] = cacc[r];
    }
}

// y = LN( [bf16(ctx)|bf16(arel)] @ BcatT^T + bo + x ). 16 rows/block, 4 waves,
// wave w -> cols [w*32, w*32+32). Fragments direct from global (L2-hot).
__global__ __launch_bounds__(256) void ln_gemm(
    const float* __restrict__ ctx, const float* __restrict__ arel,
    const short* __restrict__ BcatT, const float* __restrict__ bo,
    const float* __restrict__ X, const float* __restrict__ gamma,
    const float* __restrict__ beta, float* __restrict__ y)
{
    __shared__ float rs1[16][4];
    __shared__ float rs2[16][4];
    const int tid = threadIdx.x;
    const int w = tid >> 6, lane = tid & 63;
    const int quad = lane >> 4, l15 = lane & 15;
    const int rows0 = blockIdx.x * 16;
    const int arow = rows0 + l15;      // A row this lane loads

    f32x4 acc[2] = {};
#pragma unroll
    for (int kk = 0; kk < 9; ++kk) {
        // A-frag: rows0+l15, k = kk*32 + quad*8 + j
        bf16x8 a;
        if (kk < 4) {
            const float* src = ctx + (size_t)arow * 128 + kk * 32 + quad * 8;
            float4 w0 = *(const float4*)src, w1 = *(const float4*)(src + 4);
            short t[8] = { f2bf(w0.x), f2bf(w0.y), f2bf(w0.z), f2bf(w0.w),
                           f2bf(w1.x), f2bf(w1.y), f2bf(w1.z), f2bf(w1.w) };
            __builtin_memcpy(&a, t, 16);
        } else if (kk < 8) {
            const float* src = arel + (size_t)arow * RLD + (kk - 4) * 32 + quad * 8;
            float4 w0 = *(const float4*)src, w1 = *(const float4*)(src + 4);
            short t[8] = { f2bf(w0.x), f2bf(w0.y), f2bf(w0.z), f2bf(w0.w),
                           f2bf(w1.x), f2bf(w1.y), f2bf(w1.z), f2bf(w1.w) };
            __builtin_memcpy(&a, t, 16);
        } else {
            short t[8] = {0,0,0,0,0,0,0,0};
            if (quad == 0) {
                float4 w0 = *(const float4*)(arel + (size_t)arow * RLD + 128);
                t[0] = f2bf(w0.x); t[1] = f2bf(w0.y); t[2] = f2bf(w0.z); t[3] = f2bf(w0.w);
            }
            __builtin_memcpy(&a, t, 16);
        }
#pragma unroll
        for (int t2 = 0; t2 < 2; ++t2) {
            int n = (w * 2 + t2) * 16 + l15;
            bf16x8 b = *(const bf16x8*)(BcatT + (size_t)n * 320 + kk * 32 + quad * 8);
            acc[t2] = __builtin_amdgcn_mfma_f32_16x16x32_bf16(a, b, acc[t2], 0, 0, 0);
        }
    }

    // epilogue: +bo +x, cross-wave LayerNorm, f32 y
    float vv[2][4];
#pragma unroll
    for (int t2 = 0; t2 < 2; ++t2) {
        int col = w * 32 + t2 * 16 + l15;
        float bv = bo[col], gv;
        (void)gv;
#pragma unroll
        for (int r = 0; r < 4; ++r) {
            int grow = rows0 + quad * 4 + r;
            vv[t2][r] = acc[t2][r] + bv + X[(size_t)grow * 128 + col];
        }
    }
#pragma unroll
    for (int r = 0; r < 4; ++r) {
        float s = vv[0][r] + vv[1][r];
#pragma unroll
        for (int m = 1; m < 16; m <<= 1) s += __shfl_xor(s, m);
        if (l15 == 0) rs1[quad * 4 + r][w] = s;
    }
    __syncthreads();
    float mu[4];
#pragma unroll
    for (int r = 0; r < 4; ++r) {
        int lr = quad * 4 + r;
        mu[r] = (rs1[lr][0] + rs1[lr][1] + rs1[lr][2] + rs1[lr][3]) * (1.f / 128.f);
    }
#pragma unroll
    for (int r = 0; r < 4; ++r) {
        float d0 = vv[0][r] - mu[r], d1 = vv[1][r] - mu[r];
        float s = d0 * d0 + d1 * d1;
#pragma unroll
        for (int m = 1; m < 16; m <<= 1) s += __shfl_xor(s, m);
        if (l15 == 0) rs2[quad * 4 + r][w] = s;
    }
    __syncthreads();
#pragma unroll
    for (int r = 0; r < 4; ++r) {
        int lr = quad * 4 + r;
        int grow = rows0 + lr;
        float var = (rs2[lr][0] + rs2[lr][1] + rs2[lr][2] + rs2[lr][3]) * (1.f / 128.f);
        float inv = rsqrtf(var + 1e-5f);
#pragma unroll
        for (int t2 = 0; t2 < 2; ++t2) {
            int col = w * 32 + t2 * 16 + l15;
            y[(size_t)grow * 128 + col] = (vv[t2][r] - mu[r]) * inv * gamma[col] + beta[col];
        }
    }
}

extern "C" void kernel_launch(void* const* d_in, const int* in_sizes, int n_in,
                              void* d_out, int out_size, void* d_ws, size_t ws_size,
                              hipStream_t stream) {
    const float* x     = (const float*)d_in[0];
    const float* Wq    = (const float*)d_in[1];
    const float* bq    = (const float*)d_in[2];
    const float* Wk    = (const float*)d_in[3];
    const float* bk    = (const float*)d_in[4];
    const float* Wv    = (const float*)d_in[5];
    const float* bv    = (const float*)d_in[6];
    const float* rel_k = (const float*)d_in[7];
    const float* rel_v = (const float*)d_in[8];
    const float* Wo    = (const float*)d_in[9];
    const float* bo    = (const float*)d_in[10];
    const float* gamma = (const float*)d_in[11];
    const float* beta  = (const float*)d_in[12];

    // Workspace: 14,910,208 B (proven footprint).
    char* ws = (char*)d_ws;
    short* qh     = (short*)(ws + 0);          // 8192x128 bf16 [0,2M)
    short* kh     = (short*)(ws + 2097152);    // [2M,4M)
    short* vT     = (short*)(ws + 4194304);    // 8x128x1024 bf16 [4M,6M)
    short* qcat   = (short*)(ws + 6291456);    // 8192x256 bf16 hi|lo [6M,10M)
    float* qrel   = (float*)(ws + 10485760);   // 8192x132 f32; arel overlays per-row
    short* relcat = (short*)(ws + 14811136);   // 129x384 bf16
    short* BcatT  = (short*)relcat;            // 128x320 bf16 — built after qrel_gemm
    float* ctx    = (float*)qcat;              // 8192x128 f32 — qcat dead after qrel_gemm

    float* y_out = (float*)d_out;
    float* attn  = (float*)d_out + YEL;        // 8x1024x1024 f32

    build_relcat<<<dim3(Rn), 384, 0, stream>>>(rel_k, relcat);
    proj<<<dim3(128, 3), 256, 0, stream>>>(x, Wq, bq, Wk, bk, Wv, bv, qh, qcat, kh, vT);
    qrel_gemm<<<dim3(128, 3), 256, 0, stream>>>(qcat, relcat, qrel);
    build_bcat<<<dim3(160), 256, 0, stream>>>(rel_v, Wo, BcatT);

    // fused scores+softmax+arel+ctx: 16-row strips
    fused_attn<<<dim3(64, 1, Bn), 512, 0, stream>>>(qh, kh, vT, qrel, attn, qrel, ctx);

    // y = LN([ctx|arel] @ [Wo; rel_v@Wo] + bo + x)
    ln_gemm<<<dim3(512), 256, 0, stream>>>(ctx, qrel, BcatT, bo, x, gamma, beta, y_out);
}

// Round 7
// 172.503 us; speedup vs baseline: 2.2838x; 1.0470x over previous
//
#include <hip/hip_runtime.h>

// B=8, S=1024, H=128, rel rows R=129. All inputs/outputs are float32.
constexpr int Bn = 8, Sn = 1024, Hn = 128, Rn = 129, RLD = 132;
constexpr float INV_SCALE = 0.088388347648318447f; // 1/sqrt(128)
constexpr size_t YEL = (size_t)Bn * Sn * Hn;       // y output elements

typedef short bf16x8 __attribute__((ext_vector_type(8)));
typedef short v4s __attribute__((ext_vector_type(4)));
typedef float f32x4 __attribute__((ext_vector_type(4)));
typedef int v4i __attribute__((ext_vector_type(4)));

__device__ __forceinline__ float bf2f(short s) {
    unsigned u = ((unsigned)(unsigned short)s) << 16;
    float f; __builtin_memcpy(&f, &u, 4); return f;
}
__device__ __forceinline__ short f2bf(float f) {
    unsigned u; __builtin_memcpy(&u, &f, 4);
    unsigned r = (u + 0x7fffu + ((u >> 16) & 1u)) >> 16;
    return (short)(r & 0xffffu);
}

// relcat[p] = [rh(128) | rh(128) | rl(128)]  — K=384 companion of [qh|ql|qh]
__global__ __launch_bounds__(384) void build_relcat(
    const float* __restrict__ rel_k, short* __restrict__ relcat)
{
    const int p = blockIdx.x, c = threadIdx.x;
    const int j = (c < 256) ? (c & 127) : (c - 256);
    float v = rel_k[p * Hn + j];
    short h = f2bf(v);
    relcat[p * 384 + c] = (c < 256) ? h : f2bf(v - bf2f(h));
}

// BcatT[n][k] (ld 320): k<128 -> Wo[k][n]; 128<=k<257 -> (rel_v@Wo)[k-128][n]; else 0
__global__ __launch_bounds__(256) void build_bcat(
    const float* __restrict__ rel_v, const float* __restrict__ Wo,
    short* __restrict__ BcatT)
{
    int idx = blockIdx.x * 256 + threadIdx.x;     // 0..40959 (320x128)
    int k = idx >> 7, n = idx & 127;
    float v;
    if (k < 128) v = Wo[k * Hn + n];
    else if (k < 257) {
        int p = k - 128; float a = 0.f;
        for (int h = 0; h < Hn; ++h) a += rel_v[p * Hn + h] * Wo[h * Hn + n];
        v = a;
    } else v = 0.f;
    BcatT[n * 320 + k] = f2bf(v);
}

// Fused fp32 VALU projections: y-dim selects Q (hi/lo qcat + qh), K (kh), V (vT).
__global__ __launch_bounds__(256) void proj(
    const float* __restrict__ X,
    const float* __restrict__ Wq, const float* __restrict__ bq,
    const float* __restrict__ Wk, const float* __restrict__ bk,
    const float* __restrict__ Wv, const float* __restrict__ bv,
    short* __restrict__ qh, short* __restrict__ qcat,
    short* __restrict__ kh, short* __restrict__ vT)
{
    __shared__ float xs[64][128];
    __shared__ float wsm[32][128];
    const int tid = threadIdx.x;
    const int sel = blockIdx.y;
    const int row0 = blockIdx.x * 64;
    const float* W = (sel == 0) ? Wq : (sel == 1) ? Wk : Wv;
    const float* bias = (sel == 0) ? bq : (sel == 1) ? bk : bv;

#pragma unroll
    for (int it = 0; it < 8; ++it) {
        int u = tid + it * 256;
        int r = u >> 5, c4 = (u & 31) * 4;
        *(float4*)&xs[r][c4] = *(const float4*)(X + (size_t)(row0 + r) * 128 + c4);
    }

    const int rg = tid >> 5, cg = tid & 31;
    float acc[8][4] = {};
    for (int kc = 0; kc < 128; kc += 32) {
#pragma unroll
        for (int it = 0; it < 4; ++it) {
            int u = tid + it * 256;
            int kk = u >> 5, c4 = (u & 31) * 4;
            *(float4*)&wsm[kk][c4] = *(const float4*)(W + (size_t)(kc + kk) * 128 + c4);
        }
        __syncthreads();
#pragma unroll 8
        for (int kk = 0; kk < 32; ++kk) {
            float wv[4];
#pragma unroll
            for (int c = 0; c < 4; ++c) wv[c] = wsm[kk][cg + c * 32];
#pragma unroll
            for (int r = 0; r < 8; ++r) {
                float xv = xs[rg * 8 + r][kc + kk];
#pragma unroll
                for (int c = 0; c < 4; ++c) acc[r][c] += xv * wv[c];
            }
        }
        __syncthreads();
    }

#pragma unroll
    for (int c = 0; c < 4; ++c) {
        int col = cg + c * 32;
        float bv2 = bias[col];
#pragma unroll
        for (int r = 0; r < 8; ++r) {
            int row = row0 + rg * 8 + r;
            float v = acc[r][c] + bv2;
            short h = f2bf(v);
            if (sel == 0) {
                qh[(size_t)row * 128 + col] = h;
                qcat[(size_t)row * 256 + col] = h;
                qcat[(size_t)row * 256 + 128 + col] = f2bf(v - bf2f(h));
            } else if (sel == 1) {
                kh[(size_t)row * 128 + col] = h;
            } else {
                int b = row >> 10, i = row & (Sn - 1);
                vT[(size_t)b * 131072 + (size_t)col * 1024 + i] = h;
            }
        }
    }
}

// qrel = [qh|ql|qh] @ [rh|rh|rl]^T  (K=384, f32-faithful q), 64x64 tiles
__global__ __launch_bounds__(256) void qrel_gemm(
    const short* __restrict__ qcat, const short* __restrict__ relcat,
    float* __restrict__ qrel)
{
    __shared__ short As[64][72];
    __shared__ short Bs[64][72];
    const int tid = threadIdx.x;
    const int wave = tid >> 6, lane = tid & 63;
    const int quad = lane >> 4, l15 = lane & 15;
    const int row0 = blockIdx.x * 64, col0 = blockIdx.y * 64;

    f32x4 acc[4] = {};
    for (int kc = 0; kc < 384; kc += 64) {
#pragma unroll
        for (int it = 0; it < 2; ++it) {
            int u = tid + it * 256;
            int r = u >> 3, c8 = (u & 7) * 8;
            int srcc = kc + c8;
            if (srcc >= 256) srcc -= 256;
            *(v4i*)&As[r][c8] = *(const v4i*)(qcat + (size_t)(row0 + r) * 256 + srcc);
        }
#pragma unroll
        for (int it = 0; it < 2; ++it) {
            int u = tid + it * 256;
            int r = u >> 3, c8 = (u & 7) * 8;
            v4i val = {0, 0, 0, 0};
            if (col0 + r < Rn)
                val = *(const v4i*)(relcat + (size_t)(col0 + r) * 384 + kc + c8);
            *(v4i*)&Bs[r][c8] = val;
        }
        __syncthreads();
#pragma unroll
        for (int ks = 0; ks < 64; ks += 32) {
            bf16x8 af = *(const bf16x8*)&As[wave * 16 + l15][ks + quad * 8];
#pragma unroll
            for (int nt = 0; nt < 4; ++nt) {
                bf16x8 bf = *(const bf16x8*)&Bs[nt * 16 + l15][ks + quad * 8];
                acc[nt] = __builtin_amdgcn_mfma_f32_16x16x32_bf16(af, bf, acc[nt], 0, 0, 0);
            }
        }
        __syncthreads();
    }
    const int rloc0 = wave * 16 + quad * 4;
#pragma unroll
    for (int nt = 0; nt < 4; ++nt) {
        int col = col0 + nt * 16 + l15;
#pragma unroll
        for (int r = 0; r < 4; ++r) {
            if (col < Rn)
                qrel[(size_t)(row0 + rloc0 + r) * RLD + col] = acc[nt][r];
        }
    }
}

// Fused scores+softmax+arel+ctx per 16-row strip, scores held in REGISTERS.
// 512 threads (8 waves); wave w owns score cols [w*128,(w+1)*128).
// LDS: Pb bf16 [16][1048] (33,536 B) + QrL f32 [16][132] (8,448) + reds (2,048)
//   = 44,032 B -> 3 blocks/CU. launch_bounds(512,4) -> VGPR cap 128 for deep
//   prefetch (round-6's 60-VGPR compile strangled the load pipeline).
__global__ __launch_bounds__(512, 4) void fused_attn(
    const short* __restrict__ qh, const short* __restrict__ kh,
    const short* __restrict__ vT, const float* __restrict__ qrel_g,
    float* __restrict__ attn_g, float* __restrict__ arel_g,
    float* __restrict__ ctx_g)
{
    __shared__ __align__(16) short Pb[16][1048];   // pad 1048: writes & b128 reads <=2-way
    __shared__ float QrL[16][132];
    __shared__ float redM[16][8], redS[16][8], redL[16][8], redH[16][8];

    const int tid = threadIdx.x;
    const int w = tid >> 6, lane = tid & 63;
    const int quad = lane >> 4, l15 = lane & 15;
    const int bz = blockIdx.z;
    const int row0 = blockIdx.x * 16;
    const size_t grow0 = (size_t)bz * Sn + row0;

    // stage qrel strip (wave w: rows 2w, 2w+1)
#pragma unroll
    for (int rr = 0; rr < 2; ++rr) {
        int r = w * 2 + rr;
        const float* src = qrel_g + (grow0 + r) * RLD;
        QrL[r][lane] = src[lane];
        QrL[r][lane + 64] = src[lane + 64];
        if (lane < 4) QrL[r][128 + lane] = src[128 + lane];
    }

    // A-frags: qh rows grow0+l15
    bf16x8 afr[4];
#pragma unroll
    for (int kk = 0; kk < 4; ++kk)
        afr[kk] = *(const bf16x8*)(qh + (grow0 + l15) * 128 + kk * 32 + quad * 8);

    // phase 1: scores into registers, B double-buffered
    const short* khb = kh + (size_t)bz * Sn * 128;
    f32x4 acc[8] = {};
    bf16x8 bb[2][4];
#pragma unroll
    for (int kk = 0; kk < 4; ++kk)
        bb[0][kk] = *(const bf16x8*)(khb + (size_t)(w * 128 + l15) * 128 + kk * 32 + quad * 8);
#pragma unroll
    for (int nt = 0; nt < 8; ++nt) {
        int cur = nt & 1;
        if (nt < 7) {
#pragma unroll
            for (int kk = 0; kk < 4; ++kk)
                bb[cur ^ 1][kk] = *(const bf16x8*)(khb +
                    (size_t)(w * 128 + (nt + 1) * 16 + l15) * 128 + kk * 32 + quad * 8);
        }
#pragma unroll
        for (int kk = 0; kk < 4; ++kk)
            acc[nt] = __builtin_amdgcn_mfma_f32_16x16x32_bf16(afr[kk], bb[cur][kk], acc[nt], 0, 0, 0);
    }
    __syncthreads();   // QrL ready

    // epilogue (scale + qrel) and row-max
    float mx[4];
#pragma unroll
    for (int r = 0; r < 4; ++r) {
        int lr = quad * 4 + r, i = row0 + lr;
        float m = -3.4e38f;
#pragma unroll
        for (int nt = 0; nt < 8; ++nt) {
            int col = w * 128 + nt * 16 + l15;
            int d = col - i; d = (d < -64) ? -64 : (d > 64 ? 64 : d);
            float v = acc[nt][r] * INV_SCALE + QrL[lr][d + 64];
            acc[nt][r] = v;
            m = fmaxf(m, v);
        }
#pragma unroll
        for (int msk = 1; msk < 16; msk <<= 1) m = fmaxf(m, __shfl_xor(m, msk));
        if (l15 == 0) redM[lr][w] = m;
    }
    __syncthreads();
#pragma unroll
    for (int r = 0; r < 4; ++r) {
        int lr = quad * 4 + r;
        float m = redM[lr][0];
#pragma unroll
        for (int j = 1; j < 8; ++j) m = fmaxf(m, redM[lr][j]);
        mx[r] = m;
    }

    // exp + partial sums (s, lo, hi)
#pragma unroll
    for (int r = 0; r < 4; ++r) {
        int lr = quad * 4 + r, i = row0 + lr;
        float s = 0.f, lo = 0.f, hi = 0.f;
#pragma unroll
        for (int nt = 0; nt < 8; ++nt) {
            float e = __expf(acc[nt][r] - mx[r]);
            acc[nt][r] = e;
            s += e;
            int col = w * 128 + nt * 16 + l15;
            lo += (col <= i - 64) ? e : 0.f;
            hi += (col >= i + 64) ? e : 0.f;
        }
#pragma unroll
        for (int msk = 1; msk < 16; msk <<= 1) {
            s += __shfl_xor(s, msk);
            lo += __shfl_xor(lo, msk);
            hi += __shfl_xor(hi, msk);
        }
        if (l15 == 0) { redS[lr][w] = s; redL[lr][w] = lo; redH[lr][w] = hi; }
    }
    __syncthreads();

    // normalize; store attn f32 (exact) + Pb bf16
#pragma unroll
    for (int r = 0; r < 4; ++r) {
        int lr = quad * 4 + r;
        float s = 0.f;
#pragma unroll
        for (int j = 0; j < 8; ++j) s += redS[lr][j];
        float inv = 1.0f / s;
        float* arow = attn_g + (grow0 + lr) * Sn;
#pragma unroll
        for (int nt = 0; nt < 8; ++nt) {
            int col = w * 128 + nt * 16 + l15;
            float v = acc[nt][r] * inv;
            arow[col] = v;
            Pb[lr][col] = f2bf(v);
        }
    }
    __syncthreads();   // Pb complete

    // arel (wave w: rows 2w, 2w+1): band from Pb, lo/hi from f32 sums
#pragma unroll
    for (int rr = 0; rr < 2; ++rr) {
        int lr = w * 2 + rr, i = row0 + lr;
        float s = 0.f, lo = 0.f, hi = 0.f;
#pragma unroll
        for (int j = 0; j < 8; ++j) { s += redS[lr][j]; lo += redL[lr][j]; hi += redH[lr][j]; }
        float inv = 1.0f / s;
        float* arow = arel_g + (grow0 + lr) * RLD;
        float v0;
        if (lane == 0) v0 = lo * inv;
        else { int c = i + lane - 64; v0 = (c >= 0 && c < Sn) ? bf2f(Pb[lr][c]) : 0.f; }
        arow[lane] = v0;
        int c1 = i + lane;
        arow[lane + 64] = (c1 < Sn) ? bf2f(Pb[lr][c1]) : 0.f;
        if (lane < 4) arow[128 + lane] = (lane == 0) ? hi * inv : 0.f;
    }

    // phase 3: ctx[:, w*16..+16) = P @ v over full K (A from LDS, B from L2-hot vT)
    f32x4 cacc = {};
    const short* vtb = vT + (size_t)bz * 131072 + (size_t)(w * 16 + l15) * 1024;
#pragma unroll 8
    for (int kk = 0; kk < 32; ++kk) {
        bf16x8 a = *(const bf16x8*)&Pb[l15][kk * 32 + quad * 8];
        bf16x8 b = *(const bf16x8*)(vtb + kk * 32 + quad * 8);
        cacc = __builtin_amdgcn_mfma_f32_16x16x32_bf16(a, b, cacc, 0, 0, 0);
    }
#pragma unroll
    for (int r = 0; r < 4; ++r)
        ctx_g[(grow0 + quad * 4 + r) * 128 + w * 16 + l15] = cacc[r];
}

// y = LN( [bf16(ctx)|bf16(arel)] @ BcatT^T + bo + x ). 16 rows/block, 4 waves,
// wave w -> cols [w*32, w*32+32). Fragments direct from global (L2-hot).
__global__ __launch_bounds__(256, 4) void ln_gemm(
    const float* __restrict__ ctx, const float* __restrict__ arel,
    const short* __restrict__ BcatT, const float* __restrict__ bo,
    const float* __restrict__ X, const float* __restrict__ gamma,
    const float* __restrict__ beta, float* __restrict__ y)
{
    __shared__ float rs1[16][4];
    __shared__ float rs2[16][4];
    const int tid = threadIdx.x;
    const int w = tid >> 6, lane = tid & 63;
    const int quad = lane >> 4, l15 = lane & 15;
    const int rows0 = blockIdx.x * 16;
    const int arow = rows0 + l15;      // A row this lane loads

    f32x4 acc[2] = {};
#pragma unroll
    for (int kk = 0; kk < 9; ++kk) {
        bf16x8 a;
        if (kk < 4) {
            const float* src = ctx + (size_t)arow * 128 + kk * 32 + quad * 8;
            float4 w0 = *(const float4*)src, w1 = *(const float4*)(src + 4);
            short t[8] = { f2bf(w0.x), f2bf(w0.y), f2bf(w0.z), f2bf(w0.w),
                           f2bf(w1.x), f2bf(w1.y), f2bf(w1.z), f2bf(w1.w) };
            __builtin_memcpy(&a, t, 16);
        } else if (kk < 8) {
            const float* src = arel + (size_t)arow * RLD + (kk - 4) * 32 + quad * 8;
            float4 w0 = *(const float4*)src, w1 = *(const float4*)(src + 4);
            short t[8] = { f2bf(w0.x), f2bf(w0.y), f2bf(w0.z), f2bf(w0.w),
                           f2bf(w1.x), f2bf(w1.y), f2bf(w1.z), f2bf(w1.w) };
            __builtin_memcpy(&a, t, 16);
        } else {
            short t[8] = {0,0,0,0,0,0,0,0};
            if (quad == 0) {
                float4 w0 = *(const float4*)(arel + (size_t)arow * RLD + 128);
                t[0] = f2bf(w0.x); t[1] = f2bf(w0.y); t[2] = f2bf(w0.z); t[3] = f2bf(w0.w);
            }
            __builtin_memcpy(&a, t, 16);
        }
#pragma unroll
        for (int t2 = 0; t2 < 2; ++t2) {
            int n = (w * 2 + t2) * 16 + l15;
            bf16x8 b = *(const bf16x8*)(BcatT + (size_t)n * 320 + kk * 32 + quad * 8);
            acc[t2] = __builtin_amdgcn_mfma_f32_16x16x32_bf16(a, b, acc[t2], 0, 0, 0);
        }
    }

    float vv[2][4];
#pragma unroll
    for (int t2 = 0; t2 < 2; ++t2) {
        int col = w * 32 + t2 * 16 + l15;
        float bv = bo[col];
#pragma unroll
        for (int r = 0; r < 4; ++r) {
            int grow = rows0 + quad * 4 + r;
            vv[t2][r] = acc[t2][r] + bv + X[(size_t)grow * 128 + col];
        }
    }
#pragma unroll
    for (int r = 0; r < 4; ++r) {
        float s = vv[0][r] + vv[1][r];
#pragma unroll
        for (int m = 1; m < 16; m <<= 1) s += __shfl_xor(s, m);
        if (l15 == 0) rs1[quad * 4 + r][w] = s;
    }
    __syncthreads();
    float mu[4];
#pragma unroll
    for (int r = 0; r < 4; ++r) {
        int lr = quad * 4 + r;
        mu[r] = (rs1[lr][0] + rs1[lr][1] + rs1[lr][2] + rs1[lr][3]) * (1.f / 128.f);
    }
#pragma unroll
    for (int r = 0; r < 4; ++r) {
        float d0 = vv[0][r] - mu[r], d1 = vv[1][r] - mu[r];
        float s = d0 * d0 + d1 * d1;
#pragma unroll
        for (int m = 1; m < 16; m <<= 1) s += __shfl_xor(s, m);
        if (l15 == 0) rs2[quad * 4 + r][w] = s;
    }
    __syncthreads();
#pragma unroll
    for (int r = 0; r < 4; ++r) {
        int lr = quad * 4 + r;
        int grow = rows0 + lr;
        float var = (rs2[lr][0] + rs2[lr][1] + rs2[lr][2] + rs2[lr][3]) * (1.f / 128.f);
        float inv = rsqrtf(var + 1e-5f);
#pragma unroll
        for (int t2 = 0; t2 < 2; ++t2) {
            int col = w * 32 + t2 * 16 + l15;
            y[(size_t)grow * 128 + col] = (vv[t2][r] - mu[r]) * inv * gamma[col] + beta[col];
        }
    }
}

extern "C" void kernel_launch(void* const* d_in, const int* in_sizes, int n_in,
                              void* d_out, int out_size, void* d_ws, size_t ws_size,
                              hipStream_t stream) {
    const float* x     = (const float*)d_in[0];
    const float* Wq    = (const float*)d_in[1];
    const float* bq    = (const float*)d_in[2];
    const float* Wk    = (const float*)d_in[3];
    const float* bk    = (const float*)d_in[4];
    const float* Wv    = (const float*)d_in[5];
    const float* bv    = (const float*)d_in[6];
    const float* rel_k = (const float*)d_in[7];
    const float* rel_v = (const float*)d_in[8];
    const float* Wo    = (const float*)d_in[9];
    const float* bo    = (const float*)d_in[10];
    const float* gamma = (const float*)d_in[11];
    const float* beta  = (const float*)d_in[12];

    // Workspace: 14,910,208 B (proven footprint).
    char* ws = (char*)d_ws;
    short* qh     = (short*)(ws + 0);          // 8192x128 bf16 [0,2M)
    short* kh     = (short*)(ws + 2097152);    // [2M,4M)
    short* vT     = (short*)(ws + 4194304);    // 8x128x1024 bf16 [4M,6M)
    short* qcat   = (short*)(ws + 6291456);    // 8192x256 bf16 hi|lo [6M,10M)
    float* qrel   = (float*)(ws + 10485760);   // 8192x132 f32; arel overlays per-row
    short* relcat = (short*)(ws + 14811136);   // 129x384 bf16
    short* BcatT  = (short*)relcat;            // 128x320 bf16 — built after qrel_gemm
    float* ctx    = (float*)qcat;              // 8192x128 f32 — qcat dead after qrel_gemm

    float* y_out = (float*)d_out;
    float* attn  = (float*)d_out + YEL;        // 8x1024x1024 f32

    build_relcat<<<dim3(Rn), 384, 0, stream>>>(rel_k, relcat);
    proj<<<dim3(128, 3), 256, 0, stream>>>(x, Wq, bq, Wk, bk, Wv, bv, qh, qcat, kh, vT);
    qrel_gemm<<<dim3(128, 3), 256, 0, stream>>>(qcat, relcat, qrel);
    build_bcat<<<dim3(160), 256, 0, stream>>>(rel_v, Wo, BcatT);

    // fused scores+softmax+arel+ctx: 16-row strips, registers-resident scores
    fused_attn<<<dim3(64, 1, Bn), 512, 0, stream>>>(qh, kh, vT, qrel, attn, qrel, ctx);

    // y = LN([ctx|arel] @ [Wo; rel_v@Wo] + bo + x)
    ln_gemm<<<dim3(512), 256, 0, stream>>>(ctx, qrel, BcatT, bo, x, gamma, beta, y_out);
}

// Round 9
// 160.354 us; speedup vs baseline: 2.4569x; 1.0758x over previous
//
#include <hip/hip_runtime.h>

// B=8, S=1024, H=128, rel rows R=129. All inputs/outputs are float32.
constexpr int Bn = 8, Sn = 1024, Hn = 128, Rn = 129, RLD = 132;
constexpr float INV_SCALE = 0.088388347648318447f; // 1/sqrt(128)
constexpr size_t YEL = (size_t)Bn * Sn * Hn;       // y output elements

typedef short bf16x8 __attribute__((ext_vector_type(8)));
typedef short v4s __attribute__((ext_vector_type(4)));
typedef float f32x4 __attribute__((ext_vector_type(4)));
typedef int v4i __attribute__((ext_vector_type(4)));

__device__ __forceinline__ float bf2f(short s) {
    unsigned u = ((unsigned)(unsigned short)s) << 16;
    float f; __builtin_memcpy(&f, &u, 4); return f;
}
__device__ __forceinline__ short f2bf(float f) {
    unsigned u; __builtin_memcpy(&u, &f, 4);
    unsigned r = (u + 0x7fffu + ((u >> 16) & 1u)) >> 16;
    return (short)(r & 0xffffu);
}

// relcat[p] = [rh(128) | rh(128) | rl(128)]  — K=384 companion of [qh|ql|qh]
__global__ __launch_bounds__(384) void build_relcat(
    const float* __restrict__ rel_k, short* __restrict__ relcat)
{
    const int p = blockIdx.x, c = threadIdx.x;
    const int j = (c < 256) ? (c & 127) : (c - 256);
    float v = rel_k[p * Hn + j];
    short h = f2bf(v);
    relcat[p * 384 + c] = (c < 256) ? h : f2bf(v - bf2f(h));
}

// BcatT[n][k] (ld 320): k<128 -> Wo[k][n]; 128<=k<257 -> (rel_v@Wo)[k-128][n]; else 0
__global__ __launch_bounds__(256) void build_bcat(
    const float* __restrict__ rel_v, const float* __restrict__ Wo,
    short* __restrict__ BcatT)
{
    int idx = blockIdx.x * 256 + threadIdx.x;     // 0..40959 (320x128)
    int k = idx >> 7, n = idx & 127;
    float v;
    if (k < 128) v = Wo[k * Hn + n];
    else if (k < 257) {
        int p = k - 128; float a = 0.f;
        for (int h = 0; h < Hn; ++h) a += rel_v[p * Hn + h] * Wo[h * Hn + n];
        v = a;
    } else v = 0.f;
    BcatT[n * 320 + k] = f2bf(v);
}

// Fused fp32 VALU projections: y-dim selects Q (hi/lo qcat + qh), K (kh), V (vT).
__global__ __launch_bounds__(256) void proj(
    const float* __restrict__ X,
    const float* __restrict__ Wq, const float* __restrict__ bq,
    const float* __restrict__ Wk, const float* __restrict__ bk,
    const float* __restrict__ Wv, const float* __restrict__ bv,
    short* __restrict__ qh, short* __restrict__ qcat,
    short* __restrict__ kh, short* __restrict__ vT)
{
    __shared__ float xs[64][128];
    __shared__ float wsm[32][128];
    const int tid = threadIdx.x;
    const int sel = blockIdx.y;
    const int row0 = blockIdx.x * 64;
    const float* W = (sel == 0) ? Wq : (sel == 1) ? Wk : Wv;
    const float* bias = (sel == 0) ? bq : (sel == 1) ? bk : bv;

#pragma unroll
    for (int it = 0; it < 8; ++it) {
        int u = tid + it * 256;
        int r = u >> 5, c4 = (u & 31) * 4;
        *(float4*)&xs[r][c4] = *(const float4*)(X + (size_t)(row0 + r) * 128 + c4);
    }

    const int rg = tid >> 5, cg = tid & 31;
    float acc[8][4] = {};
    for (int kc = 0; kc < 128; kc += 32) {
#pragma unroll
        for (int it = 0; it < 4; ++it) {
            int u = tid + it * 256;
            int kk = u >> 5, c4 = (u & 31) * 4;
            *(float4*)&wsm[kk][c4] = *(const float4*)(W + (size_t)(kc + kk) * 128 + c4);
        }
        __syncthreads();
#pragma unroll 8
        for (int kk = 0; kk < 32; ++kk) {
            float wv[4];
#pragma unroll
            for (int c = 0; c < 4; ++c) wv[c] = wsm[kk][cg + c * 32];
#pragma unroll
            for (int r = 0; r < 8; ++r) {
                float xv = xs[rg * 8 + r][kc + kk];
#pragma unroll
                for (int c = 0; c < 4; ++c) acc[r][c] += xv * wv[c];
            }
        }
        __syncthreads();
    }

#pragma unroll
    for (int c = 0; c < 4; ++c) {
        int col = cg + c * 32;
        float bv2 = bias[col];
#pragma unroll
        for (int r = 0; r < 8; ++r) {
            int row = row0 + rg * 8 + r;
            float v = acc[r][c] + bv2;
            short h = f2bf(v);
            if (sel == 0) {
                qh[(size_t)row * 128 + col] = h;
                qcat[(size_t)row * 256 + col] = h;
                qcat[(size_t)row * 256 + 128 + col] = f2bf(v - bf2f(h));
            } else if (sel == 1) {
                kh[(size_t)row * 128 + col] = h;
            } else {
                int b = row >> 10, i = row & (Sn - 1);
                vT[(size_t)b * 131072 + (size_t)col * 1024 + i] = h;
            }
        }
    }
}

// qrel = [qh|ql|qh] @ [rh|rh|rl]^T  (K=384, f32-faithful q), 64x64 tiles
__global__ __launch_bounds__(256) void qrel_gemm(
    const short* __restrict__ qcat, const short* __restrict__ relcat,
    float* __restrict__ qrel)
{
    __shared__ short As[64][72];
    __shared__ short Bs[64][72];
    const int tid = threadIdx.x;
    const int wave = tid >> 6, lane = tid & 63;
    const int quad = lane >> 4, l15 = lane & 15;
    const int row0 = blockIdx.x * 64, col0 = blockIdx.y * 64;

    f32x4 acc[4] = {};
    for (int kc = 0; kc < 384; kc += 64) {
#pragma unroll
        for (int it = 0; it < 2; ++it) {
            int u = tid + it * 256;
            int r = u >> 3, c8 = (u & 7) * 8;
            int srcc = kc + c8;
            if (srcc >= 256) srcc -= 256;
            *(v4i*)&As[r][c8] = *(const v4i*)(qcat + (size_t)(row0 + r) * 256 + srcc);
        }
#pragma unroll
        for (int it = 0; it < 2; ++it) {
            int u = tid + it * 256;
            int r = u >> 3, c8 = (u & 7) * 8;
            v4i val = {0, 0, 0, 0};
            if (col0 + r < Rn)
                val = *(const v4i*)(relcat + (size_t)(col0 + r) * 384 + kc + c8);
            *(v4i*)&Bs[r][c8] = val;
        }
        __syncthreads();
#pragma unroll
        for (int ks = 0; ks < 64; ks += 32) {
            bf16x8 af = *(const bf16x8*)&As[wave * 16 + l15][ks + quad * 8];
#pragma unroll
            for (int nt = 0; nt < 4; ++nt) {
                bf16x8 bf = *(const bf16x8*)&Bs[nt * 16 + l15][ks + quad * 8];
                acc[nt] = __builtin_amdgcn_mfma_f32_16x16x32_bf16(af, bf, acc[nt], 0, 0, 0);
            }
        }
        __syncthreads();
    }
    const int rloc0 = wave * 16 + quad * 4;
#pragma unroll
    for (int nt = 0; nt < 4; ++nt) {
        int col = col0 + nt * 16 + l15;
#pragma unroll
        for (int r = 0; r < 4; ++r) {
            if (col < Rn)
                qrel[(size_t)(row0 + rloc0 + r) * RLD + col] = acc[nt][r];
        }
    }
}

// Fully fused: scores (LDS-staged kh) + softmax + attn-write + P@V (LDS-staged
// vT) + [ctx|arel]@BcatT (LDS-staged) + residual + LayerNorm -> y.
// 512 threads / 16-row strip; wave w owns score cols {kt*128 + w*16 + l15}.
// LDS 80,896 B -> 2 blocks/CU; all staging is bulk coalesced 16B loads.
__global__ __launch_bounds__(512, 4) void fused_attn(
    const short* __restrict__ qh, const short* __restrict__ kh,
    const short* __restrict__ vT, const float* __restrict__ qrel_g,
    const short* __restrict__ BcatT,
    const float* __restrict__ X, const float* __restrict__ bo,
    const float* __restrict__ gamma, const float* __restrict__ beta,
    float* __restrict__ attn_g, float* __restrict__ y_g)
{
    __shared__ __align__(16) char smem[80896];
    short* KTs  = (short*)smem;               // [128][136] staging tile (34,816 B)
    short* Pb   = (short*)(smem + 34816);     // [16][1032] bf16 P      (33,024 B)
    short* CtxA = (short*)(smem + 67840);     // [16][344]  [ctx|arel]  (11,008 B)
    float* QrL  = (float*)(smem + 67840);     // [16][132] overlays CtxA (dead before it)
    float* redM = (float*)(smem + 78848);     // 4x [16][8] reduction arrays
    float* redS = redM + 128;
    float* redL = redS + 128;
    float* redH = redL + 128;

    const int tid = threadIdx.x;
    const int w = tid >> 6, lane = tid & 63;
    const int quad = lane >> 4, l15 = lane & 15;
    const int bz = blockIdx.z;
    const int row0 = blockIdx.x * 16;
    const size_t grow0 = (size_t)bz * Sn + row0;

    // stage qrel strip into QrL (wave w: rows 2w, 2w+1)
#pragma unroll
    for (int rr = 0; rr < 2; ++rr) {
        int r = w * 2 + rr;
        const float* src = qrel_g + (grow0 + r) * RLD;
        QrL[r * 132 + lane] = src[lane];
        QrL[r * 132 + 64 + lane] = src[64 + lane];
        if (lane < 4) QrL[r * 132 + 128 + lane] = src[128 + lane];
    }

    // A-frags: qh strip rows (one-time per-lane loads)
    bf16x8 afr[4];
#pragma unroll
    for (int kk = 0; kk < 4; ++kk)
        afr[kk] = *(const bf16x8*)(qh + (grow0 + l15) * 128 + kk * 32 + quad * 8);

    // ---- phase 1: scores via LDS-staged kh tiles
    const short* khb = kh + (size_t)bz * Sn * 128;
    f32x4 acc[8] = {};
    for (int kt = 0; kt < 8; ++kt) {
#pragma unroll
        for (int it = 0; it < 4; ++it) {
            int u = tid + it * 512;
            int r = u >> 4, c8 = (u & 15) * 8;
            *(v4i*)&KTs[r * 136 + c8] = *(const v4i*)(khb + (size_t)(kt * 128 + r) * 128 + c8);
        }
        __syncthreads();
#pragma unroll
        for (int kk = 0; kk < 4; ++kk) {
            bf16x8 b = *(const bf16x8*)&KTs[(w * 16 + l15) * 136 + kk * 32 + quad * 8];
            acc[kt] = __builtin_amdgcn_mfma_f32_16x16x32_bf16(afr[kk], b, acc[kt], 0, 0, 0);
        }
        __syncthreads();
    }

    // ---- scale + qrel + row-max
    float mx[4];
#pragma unroll
    for (int r = 0; r < 4; ++r) {
        int lr = quad * 4 + r, i = row0 + lr;
        float m = -3.4e38f;
#pragma unroll
        for (int kt = 0; kt < 8; ++kt) {
            int col = kt * 128 + w * 16 + l15;
            int d = col - i; d = (d < -64) ? -64 : (d > 64 ? 64 : d);
            float v = acc[kt][r] * INV_SCALE + QrL[lr * 132 + d + 64];
            acc[kt][r] = v;
            m = fmaxf(m, v);
        }
#pragma unroll
        for (int msk = 1; msk < 16; msk <<= 1) m = fmaxf(m, __shfl_xor(m, msk));
        if (l15 == 0) redM[lr * 8 + w] = m;
    }
    __syncthreads();
#pragma unroll
    for (int r = 0; r < 4; ++r) {
        int lr = quad * 4 + r;
        float m = redM[lr * 8];
#pragma unroll
        for (int j = 1; j < 8; ++j) m = fmaxf(m, redM[lr * 8 + j]);
        mx[r] = m;
    }

    // ---- exp + partial sums (s, lo, hi)
#pragma unroll
    for (int r = 0; r < 4; ++r) {
        int lr = quad * 4 + r, i = row0 + lr;
        float s = 0.f, lo = 0.f, hi = 0.f;
#pragma unroll
        for (int kt = 0; kt < 8; ++kt) {
            float e = __expf(acc[kt][r] - mx[r]);
            acc[kt][r] = e;
            s += e;
            int col = kt * 128 + w * 16 + l15;
            lo += (col <= i - 64) ? e : 0.f;
            hi += (col >= i + 64) ? e : 0.f;
        }
#pragma unroll
        for (int msk = 1; msk < 16; msk <<= 1) {
            s += __shfl_xor(s, msk);
            lo += __shfl_xor(lo, msk);
            hi += __shfl_xor(hi, msk);
        }
        if (l15 == 0) { redS[lr * 8 + w] = s; redL[lr * 8 + w] = lo; redH[lr * 8 + w] = hi; }
    }
    __syncthreads();

    // ---- normalize; write attn f32 (required output) + Pb bf16
#pragma unroll
    for (int r = 0; r < 4; ++r) {
        int lr = quad * 4 + r;
        float s = 0.f;
#pragma unroll
        for (int j = 0; j < 8; ++j) s += redS[lr * 8 + j];
        float inv = 1.0f / s;
        float* arow = attn_g + (grow0 + lr) * Sn;
#pragma unroll
        for (int kt = 0; kt < 8; ++kt) {
            int col = kt * 128 + w * 16 + l15;
            float v = acc[kt][r] * inv;
            arow[col] = v;
            Pb[lr * 1032 + col] = f2bf(v);
        }
    }
    __syncthreads();   // Pb complete (and all QrL/score reads done)

    // ---- phase 3: ctx = P @ V via LDS-staged vT tiles
    const short* vtb = vT + (size_t)bz * 131072;
    f32x4 cacc = {};
    for (int kc = 0; kc < 8; ++kc) {
#pragma unroll
        for (int it = 0; it < 4; ++it) {
            int u = tid + it * 512;
            int r = u >> 4, c8 = (u & 15) * 8;
            *(v4i*)&KTs[r * 136 + c8] = *(const v4i*)(vtb + (size_t)r * 1024 + kc * 128 + c8);
        }
        __syncthreads();
#pragma unroll
        for (int kk = 0; kk < 4; ++kk) {
            bf16x8 a = *(const bf16x8*)&Pb[l15 * 1032 + kc * 128 + kk * 32 + quad * 8];
            bf16x8 b = *(const bf16x8*)&KTs[(w * 16 + l15) * 136 + kk * 32 + quad * 8];
            cacc = __builtin_amdgcn_mfma_f32_16x16x32_bf16(a, b, cacc, 0, 0, 0);
        }
        __syncthreads();
    }

    // ---- build CtxA = [bf16(ctx) | arel(129) | 0] in LDS (overlays dead QrL)
#pragma unroll
    for (int r = 0; r < 4; ++r)
        CtxA[(quad * 4 + r) * 344 + w * 16 + l15] = f2bf(cacc[r]);
#pragma unroll
    for (int rr = 0; rr < 2; ++rr) {
        int lr = w * 2 + rr, i = row0 + lr;
        float s = 0.f, lo = 0.f, hi = 0.f;
#pragma unroll
        for (int j = 0; j < 8; ++j) {
            s += redS[lr * 8 + j]; lo += redL[lr * 8 + j]; hi += redH[lr * 8 + j];
        }
        float inv = 1.0f / s;
        // p = lane (0..63): p==0 -> lo, else band attn[i, i+p-64]
        float v0;
        if (lane == 0) v0 = lo * inv;
        else { int c = i + lane - 64; v0 = (c >= 0 && c < Sn) ? bf2f(Pb[lr * 1032 + c]) : 0.f; }
        CtxA[lr * 344 + 128 + lane] = f2bf(v0);
        // p = lane+64 (64..127): band attn[i, i+lane]
        int c1 = i + lane;
        CtxA[lr * 344 + 192 + lane] = (c1 < Sn) ? Pb[lr * 1032 + c1] : (short)0;
        // p = lane+128 (128..191): p==128 -> hi, else 0 (covers K up to 319)
        CtxA[lr * 344 + 256 + lane] = (lane == 0) ? f2bf(hi * inv) : (short)0;
    }
    __syncthreads();

    // ---- phase 4: y = LN([ctx|arel] @ BcatT^T + bo + x), BcatT LDS-staged
    f32x4 yacc = {};
#pragma unroll
    for (int ch = 0; ch < 3; ++ch) {
        if (ch < 2) {
#pragma unroll
            for (int it = 0; it < 4; ++it) {
                int u = tid + it * 512;
                int n = u >> 4, c8 = (u & 15) * 8;
                *(v4i*)&KTs[n * 136 + c8] = *(const v4i*)(BcatT + (size_t)n * 320 + ch * 128 + c8);
            }
        } else {
            // FIX (round 8 bug): cover ALL 128 rows x 64 cols of the K=[256,320)
            // chunk. Round 8 staged only rows 0..63, leaving waves 4-7 reading
            // stale ch==1 data -> absmax 2.97.
#pragma unroll
            for (int it = 0; it < 2; ++it) {
                int u = tid + it * 512;
                int n = u >> 3, c8 = (u & 7) * 8;
                *(v4i*)&KTs[n * 136 + c8] = *(const v4i*)(BcatT + (size_t)n * 320 + 256 + c8);
            }
        }
        __syncthreads();
        const int nkk = (ch == 2) ? 2 : 4;
        for (int kk = 0; kk < nkk; ++kk) {
            bf16x8 a = *(const bf16x8*)&CtxA[l15 * 344 + ch * 128 + kk * 32 + quad * 8];
            bf16x8 b = *(const bf16x8*)&KTs[(w * 16 + l15) * 136 + kk * 32 + quad * 8];
            yacc = __builtin_amdgcn_mfma_f32_16x16x32_bf16(a, b, yacc, 0, 0, 0);
        }
        __syncthreads();
    }

    // ---- residual + LayerNorm epilogue (cross-wave via redM/redS, now free)
    const int col = w * 16 + l15;
    const float bov = bo[col], gv = gamma[col], bev = beta[col];
    float vv[4];
#pragma unroll
    for (int r = 0; r < 4; ++r) {
        int lr = quad * 4 + r;
        vv[r] = yacc[r] + bov + X[(grow0 + lr) * 128 + col];
    }
#pragma unroll
    for (int r = 0; r < 4; ++r) {
        float s = vv[r];
#pragma unroll
        for (int msk = 1; msk < 16; msk <<= 1) s += __shfl_xor(s, msk);
        if (l15 == 0) redM[(quad * 4 + r) * 8 + w] = s;
    }
    __syncthreads();
    float mu[4];
#pragma unroll
    for (int r = 0; r < 4; ++r) {
        int lr = quad * 4 + r;
        float s = 0.f;
#pragma unroll
        for (int j = 0; j < 8; ++j) s += redM[lr * 8 + j];
        mu[r] = s * (1.f / 128.f);
    }
#pragma unroll
    for (int r = 0; r < 4; ++r) {
        float d = vv[r] - mu[r];
        float s = d * d;
#pragma unroll
        for (int msk = 1; msk < 16; msk <<= 1) s += __shfl_xor(s, msk);
        if (l15 == 0) redS[(quad * 4 + r) * 8 + w] = s;
    }
    __syncthreads();
#pragma unroll
    for (int r = 0; r < 4; ++r) {
        int lr = quad * 4 + r;
        float s = 0.f;
#pragma unroll
        for (int j = 0; j < 8; ++j) s += redS[lr * 8 + j];
        float inv = rsqrtf(s * (1.f / 128.f) + 1e-5f);
        y_g[(grow0 + lr) * 128 + col] = (vv[r] - mu[r]) * inv * gv + bev;
    }
}

extern "C" void kernel_launch(void* const* d_in, const int* in_sizes, int n_in,
                              void* d_out, int out_size, void* d_ws, size_t ws_size,
                              hipStream_t stream) {
    const float* x     = (const float*)d_in[0];
    const float* Wq    = (const float*)d_in[1];
    const float* bq    = (const float*)d_in[2];
    const float* Wk    = (const float*)d_in[3];
    const float* bk    = (const float*)d_in[4];
    const float* Wv    = (const float*)d_in[5];
    const float* bv    = (const float*)d_in[6];
    const float* rel_k = (const float*)d_in[7];
    const float* rel_v = (const float*)d_in[8];
    const float* Wo    = (const float*)d_in[9];
    const float* bo    = (const float*)d_in[10];
    const float* gamma = (const float*)d_in[11];
    const float* beta  = (const float*)d_in[12];

    char* ws = (char*)d_ws;
    short* qh     = (short*)(ws + 0);          // 8192x128 bf16
    short* kh     = (short*)(ws + 2097152);
    short* vT     = (short*)(ws + 4194304);    // 8x128x1024 bf16
    short* qcat   = (short*)(ws + 6291456);    // 8192x256 bf16 hi|lo
    float* qrel   = (float*)(ws + 10485760);   // 8192x132 f32
    short* relcat = (short*)(ws + 14811136);   // 129x384 bf16
    short* BcatT  = (short*)relcat;            // 128x320 bf16 — built after qrel_gemm

    float* y_out = (float*)d_out;
    float* attn  = (float*)d_out + YEL;        // 8x1024x1024 f32

    build_relcat<<<dim3(Rn), 384, 0, stream>>>(rel_k, relcat);
    proj<<<dim3(128, 3), 256, 0, stream>>>(x, Wq, bq, Wk, bk, Wv, bv, qh, qcat, kh, vT);
    qrel_gemm<<<dim3(128, 3), 256, 0, stream>>>(qcat, relcat, qrel);
    build_bcat<<<dim3(160), 256, 0, stream>>>(rel_v, Wo, BcatT);

    fused_attn<<<dim3(64, 1, Bn), 512, 0, stream>>>(
        qh, kh, vT, qrel, BcatT, x, bo, gamma, beta, attn, y_out);
}